// Round 3
// baseline (3296.309 us; speedup 1.0000x reference)
//
#include <hip/hip_runtime.h>
#include <stdint.h>
#include <stddef.h>

typedef __attribute__((ext_vector_type(8))) short short8;
typedef __attribute__((ext_vector_type(4))) float f32x4;

__device__ inline unsigned short f2bf(float f) {
  union { float f; uint32_t u; } v; v.f = f;
  uint32_t u = v.u;
  u += 0x7FFFu + ((u >> 16) & 1u);
  return (unsigned short)(u >> 16);
}
__device__ inline float bf2f(unsigned short h) {
  union { uint32_t u; float f; } v; v.u = ((uint32_t)h) << 16; return v.f;
}
__device__ inline short8 pack8(float4 a, float4 b) {
  short8 r;
  r[0] = (short)f2bf(a.x); r[1] = (short)f2bf(a.y);
  r[2] = (short)f2bf(a.z); r[3] = (short)f2bf(a.w);
  r[4] = (short)f2bf(b.x); r[5] = (short)f2bf(b.y);
  r[6] = (short)f2bf(b.z); r[7] = (short)f2bf(b.w);
  return r;
}
__device__ inline float tanh_fast(float x) {
  float xc = fminf(fmaxf(x, -9.f), 9.f);
  float e = __expf(2.f * xc);
  return (e - 1.f) * __builtin_amdgcn_rcpf(e + 1.f);
}
__device__ inline float sigm_fast(float x) {
  float xc = fminf(fmaxf(x, -30.f), 30.f);
  return __builtin_amdgcn_rcpf(1.f + __expf(-xc));
}
// One-shot flag sync: single release store, acquire polls. No RMW contention.
__device__ inline void set_flag(int* f) {
  __hip_atomic_store(f, 1, __ATOMIC_RELEASE, __HIP_MEMORY_SCOPE_AGENT);
}
__device__ inline void wait_flag(int* f) {
  while (__hip_atomic_load(f, __ATOMIC_ACQUIRE, __HIP_MEMORY_SCOPE_AGENT) == 0)
    __builtin_amdgcn_s_sleep(1);
}

// Gather + bf16-convert embeddings.
__global__ __launch_bounds__(128) void prep_gather(
    const int* __restrict__ src, const int* __restrict__ trg,
    const float* __restrict__ emb,
    unsigned short* __restrict__ xbf, unsigned short* __restrict__ ebf,
    unsigned short* __restrict__ Zbf) {
  int r = blockIdx.x, tid = threadIdx.x;
  if (r < 2048) {
    int b = r & 31, s = r >> 5;
    int tok = src[b * 64 + s];
    const float* e = emb + (size_t)tok * 512;
    float4 v = *(const float4*)(e + tid * 4);
    unsigned short* dst = xbf + (size_t)r * 512 + tid * 4;
    dst[0] = f2bf(v.x); dst[1] = f2bf(v.y); dst[2] = f2bf(v.z); dst[3] = f2bf(v.w);
  } else {
    int rr = r - 2048;
    int t = rr >> 5, b = rr & 31;
    unsigned short* dst = ebf + (size_t)rr * 512 + tid * 4;
    if (t < 47) {
      int tok = trg[t * 32 + b];
      const float* e = emb + (size_t)tok * 512;
      float4 v = *(const float4*)(e + tid * 4);
      unsigned short q0 = f2bf(v.x), q1 = f2bf(v.y), q2 = f2bf(v.z), q3 = f2bf(v.w);
      dst[0] = q0; dst[1] = q1; dst[2] = q2; dst[3] = q3;
      unsigned short* zd = Zbf + (size_t)rr * 2048 + 1536 + tid * 4;
      zd[0] = q0; zd[1] = q1; zd[2] = q2; zd[3] = q3;
    } else {
      dst[0] = 0; dst[1] = 0; dst[2] = 0; dst[3] = 0;
    }
  }
}

__global__ __launch_bounds__(256) void cvt_f32_bf16(const float* __restrict__ src,
                                                    unsigned short* __restrict__ dst,
                                                    long long n4) {
  long long i = (long long)blockIdx.x * 256 + threadIdx.x;
  long long stride = (long long)gridDim.x * 256;
  for (; i < n4; i += stride) {
    float4 v = ((const float4*)src)[i];
    unsigned short* d = dst + i * 4;
    d[0] = f2bf(v.x); d[1] = f2bf(v.y); d[2] = f2bf(v.z); d[3] = f2bf(v.w);
  }
}

// C[m,n] = sum_k A[m,k]*B[n,k] (+bias[n]). 128x128 tile, BK=32, 4 waves.
template <bool ABF, bool BBF, bool WBF>
__global__ __launch_bounds__(256) void gemm_kernel(
    const void* __restrict__ Av, int lda,
    const void* __restrict__ Bv, int ldb, int bco,
    const float* __restrict__ bias,
    void* __restrict__ Cv, int ldc,
    int K, int Mvalid, int row_off) {
  __shared__ __align__(16) unsigned short As[128 * 32];
  __shared__ __align__(16) unsigned short Bs[128 * 32];
  const int tid = threadIdx.x;
  const int m0 = blockIdx.x * 128, n0 = blockIdx.y * 128;
  const int w = tid >> 6, lane = tid & 63;
  const int wm = w >> 1, wn = w & 1;
  const int fr = lane & 15, fq = lane >> 4;
  f32x4 acc[4][4];
#pragma unroll
  for (int mi = 0; mi < 4; ++mi)
#pragma unroll
    for (int ni = 0; ni < 4; ++ni) acc[mi][ni] = (f32x4){0.f, 0.f, 0.f, 0.f};
  for (int k0 = 0; k0 < K; k0 += 32) {
#pragma unroll
    for (int p = 0; p < 2; ++p) {
      int idx = p * 256 + tid;
      int row = idx >> 2, seg = idx & 3;
      if (ABF) {
        const unsigned short* Ab = (const unsigned short*)Av;
        *(short8*)(As + row * 32 + seg * 8) =
            *(const short8*)(Ab + (size_t)(m0 + row) * lda + k0 + seg * 8);
      } else {
        const float* Af = (const float*)Av;
        const float* ap = Af + (size_t)(m0 + row) * lda + k0 + seg * 8;
        *(short8*)(As + row * 32 + seg * 8) = pack8(*(const float4*)ap, *(const float4*)(ap + 4));
      }
      if (BBF) {
        const unsigned short* Bb = (const unsigned short*)Bv;
        *(short8*)(Bs + row * 32 + seg * 8) =
            *(const short8*)(Bb + (size_t)(n0 + row) * ldb + bco + k0 + seg * 8);
      } else {
        const float* Bf = (const float*)Bv;
        const float* bp = Bf + (size_t)(n0 + row) * ldb + bco + k0 + seg * 8;
        *(short8*)(Bs + row * 32 + seg * 8) = pack8(*(const float4*)bp, *(const float4*)(bp + 4));
      }
    }
    __syncthreads();
    short8 af[4], bfr[4];
#pragma unroll
    for (int mi = 0; mi < 4; ++mi)
      af[mi] = *(const short8*)(As + (wm * 64 + mi * 16 + fr) * 32 + fq * 8);
#pragma unroll
    for (int ni = 0; ni < 4; ++ni)
      bfr[ni] = *(const short8*)(Bs + (wn * 64 + ni * 16 + fr) * 32 + fq * 8);
#pragma unroll
    for (int mi = 0; mi < 4; ++mi)
#pragma unroll
      for (int ni = 0; ni < 4; ++ni)
        acc[mi][ni] = __builtin_amdgcn_mfma_f32_16x16x32_bf16(af[mi], bfr[ni], acc[mi][ni], 0, 0, 0);
    __syncthreads();
  }
#pragma unroll
  for (int mi = 0; mi < 4; ++mi)
#pragma unroll
    for (int ni = 0; ni < 4; ++ni) {
      int col = n0 + wn * 64 + ni * 16 + fr;
      float bv = bias ? bias[col] : 0.f;
#pragma unroll
      for (int j = 0; j < 4; ++j) {
        int rowm = m0 + wm * 64 + mi * 16 + fq * 4 + j;
        if (rowm < Mvalid) {
          float val = acc[mi][ni][j] + bv;
          if (WBF)
            ((unsigned short*)Cv)[(size_t)(rowm + row_off) * ldc + col] = f2bf(val);
          else
            ((float*)Cv)[(size_t)(rowm + row_off) * ldc + col] = val;
        }
      }
    }
}

// Bidirectional GRU encoder. 32 blocks: dir=blk>>4, 32-dim slice each.
// Whh slice LDS-resident (bf16); per-step one-shot flag sync per dir.
__global__ __launch_bounds__(512, 1) void enc_kernel(
    const float* __restrict__ Gif, const float* __restrict__ Gib,
    const float* __restrict__ whF, const float* __restrict__ whB,
    const float* __restrict__ bhhF, const float* __restrict__ bhhB,
    unsigned short* hbf,            // [dir][2][32][512]
    unsigned short* __restrict__ ebo,  // [b][s][1024] bf16
    float* __restrict__ hcat,       // [b][1024]
    int* hflag) {
  const int blk = blockIdx.x, tid = threadIdx.x;
  const int dir = blk >> 4, slice = blk & 15, D0 = slice * 32;
  const float* Whh = dir ? whB : whF;
  const float* Gi = dir ? Gib : Gif;
  const float* bhh = dir ? bhhB : bhhF;
  __shared__ __align__(16) unsigned short wlds[96 * 520];
  __shared__ __align__(16) unsigned short hlds[32 * 520];
  __shared__ __align__(16) float gl[96 * 33];
  for (int c = tid; c < 96 * 64; c += 512) {
    int lr = c >> 6, seg = c & 63;
    int gr = (lr >> 5) * 512 + D0 + (lr & 31);
    const float* wsrc = Whh + (size_t)gr * 512 + seg * 8;
    *(short8*)(wlds + lr * 520 + seg * 8) = pack8(*(const float4*)wsrc, *(const float4*)(wsrc + 4));
  }
  const int w = tid >> 6, lane = tid & 63, fr = lane & 15, fq = lane >> 4;
  unsigned short* hb0 = hbf + (size_t)dir * 2 * 32 * 512;
  int* myflags = hflag + dir * 64 * 16;
  float hprev[2] = {0.f, 0.f};
  for (int t = 0; t < 64; ++t) {
    const unsigned short* hsrc = hb0 + (t & 1) * 32 * 512;
    for (int c = tid; c < 32 * 64; c += 512) {
      int r = c >> 6, seg = c & 63;
      *(short8*)(hlds + r * 520 + seg * 8) = *(const short8*)(hsrc + r * 512 + seg * 8);
    }
    __syncthreads();
    if (w < 6) {
      f32x4 acc0 = {0.f, 0.f, 0.f, 0.f}, acc1 = {0.f, 0.f, 0.f, 0.f};
#pragma unroll
      for (int k0 = 0; k0 < 512; k0 += 32) {
        short8 bq = *(const short8*)(wlds + (w * 16 + fr) * 520 + k0 + fq * 8);
        short8 a0 = *(const short8*)(hlds + fr * 520 + k0 + fq * 8);
        short8 a1 = *(const short8*)(hlds + (16 + fr) * 520 + k0 + fq * 8);
        acc0 = __builtin_amdgcn_mfma_f32_16x16x32_bf16(a0, bq, acc0, 0, 0, 0);
        acc1 = __builtin_amdgcn_mfma_f32_16x16x32_bf16(a1, bq, acc1, 0, 0, 0);
      }
#pragma unroll
      for (int j = 0; j < 4; ++j) {
        gl[(w * 16 + fr) * 33 + fq * 4 + j] = acc0[j];
        gl[(w * 16 + fr) * 33 + 16 + fq * 4 + j] = acc1[j];
      }
    }
    __syncthreads();
    const int srow = dir ? 63 - t : t;
#pragma unroll
    for (int rep = 0; rep < 2; ++rep) {
      int idx = rep * 512 + tid, b = idx >> 5, dl = idx & 31, d = D0 + dl;
      float ar = gl[dl * 33 + b] + bhh[d];
      float az = gl[(32 + dl) * 33 + b] + bhh[512 + d];
      float an = gl[(64 + dl) * 33 + b] + bhh[1024 + d];
      const float* gi = Gi + ((size_t)srow * 32 + b) * 1536;
      float r = sigm_fast(gi[d] + ar);
      float z = sigm_fast(gi[512 + d] + az);
      float n = tanh_fast(gi[1024 + d] + r * an);
      float h2 = (1.f - z) * n + z * hprev[rep];
      hprev[rep] = h2;
      hb0[((t + 1) & 1) * 32 * 512 + b * 512 + d] = f2bf(h2);
      ebo[((size_t)b * 64 + srow) * 1024 + (size_t)dir * 512 + d] = f2bf(h2);
      if (t == 63) hcat[(size_t)b * 1024 + (size_t)dir * 512 + d] = h2;
    }
    __syncthreads();
    if (tid == 0) { __threadfence(); set_flag(&myflags[t * 16 + slice]); }
    if (t < 63) {
      if (tid < 16) wait_flag(&myflags[t * 16 + tid]);
      __syncthreads();
      __threadfence();
    }
  }
}

__global__ __launch_bounds__(512) void tanh_s0(const float* __restrict__ s0raw,
                                               float* __restrict__ s0f,
                                               unsigned short* __restrict__ sbf) {
  int idx = blockIdx.x * 512 + threadIdx.x;
  float v = tanhf(s0raw[idx]);
  s0f[idx] = v;
  sbf[idx] = f2bf(v);
}

// Decoder: blocks 0..31 = G (sproj+gh MFMA, weights LDS-resident, all batches),
// blocks 32..95 = B (2 per batch: scores+softmax dup'd; c/gic/gates col-split).
// One-shot flags; sbf double-buffered by step parity.
__global__ __launch_bounds__(512, 1) void dec_kernel(
    const float* __restrict__ attnW, const float* __restrict__ decWhh,
    const float* __restrict__ decBhh, const float* __restrict__ attnV,
    unsigned short* sbf, const float* __restrict__ s0f,
    const unsigned short* __restrict__ epf, const unsigned short* __restrict__ ebo,
    const unsigned short* __restrict__ EP2b, const float* __restrict__ Gie,
    float* gout, unsigned short* __restrict__ Zbf,
    int* gflag, int* sflag) {
  __shared__ __align__(16) char smem[100352];
  const int blk = blockIdx.x, tid = threadIdx.x;
  if (blk < 32) {
    // ---- G role: gout[b][n] for n in [g*64, g*64+64) ----
    const int g = blk;
    unsigned short* wlds = (unsigned short*)smem;                     // 64*520
    unsigned short* slds = (unsigned short*)(smem + 64 * 520 * 2);    // 32*520
    float* wbias = (float*)(smem + 64 * 520 * 2 + 32 * 520 * 2);      // 64
    for (int c = tid; c < 64 * 64; c += 512) {
      int lr = c >> 6, seg = c & 63;
      int rc = g * 64 + lr;
      const float* srcp = rc < 512 ? attnW + (size_t)rc * 1536 + seg * 8
                                   : decWhh + (size_t)(rc - 512) * 512 + seg * 8;
      *(short8*)(wlds + lr * 520 + seg * 8) = pack8(*(const float4*)srcp, *(const float4*)(srcp + 4));
    }
    if (tid < 64) {
      int rc = g * 64 + tid;
      wbias[tid] = rc < 512 ? 0.f : decBhh[rc - 512];
    }
    const int w = tid >> 6, lane = tid & 63, fr = lane & 15, fq = lane >> 4;
    const int mt = w >> 2, nt = w & 3;
    for (int t = 0; t < 47; ++t) {
      if (t > 0) {
        if (tid < 64) wait_flag(&sflag[(t - 1) * 64 + tid]);
        __syncthreads();
        __threadfence();
      }
      const unsigned short* ssrc = sbf + (t & 1) * 16384;
      for (int c = tid; c < 32 * 64; c += 512) {
        int r = c >> 6, seg = c & 63;
        *(short8*)(slds + r * 520 + seg * 8) = *(const short8*)(ssrc + r * 512 + seg * 8);
      }
      __syncthreads();
      {
        f32x4 acc = {0.f, 0.f, 0.f, 0.f};
#pragma unroll
        for (int k0 = 0; k0 < 512; k0 += 32) {
          short8 a = *(const short8*)(slds + (mt * 16 + fr) * 520 + k0 + fq * 8);
          short8 bq = *(const short8*)(wlds + (nt * 16 + fr) * 520 + k0 + fq * 8);
          acc = __builtin_amdgcn_mfma_f32_16x16x32_bf16(a, bq, acc, 0, 0, 0);
        }
        int n = g * 64 + nt * 16 + fr;
        float bv = wbias[nt * 16 + fr];
#pragma unroll
        for (int j = 0; j < 4; ++j)
          gout[(size_t)(mt * 16 + fq * 4 + j) * 2048 + n] = acc[j] + bv;
      }
      __syncthreads();
      if (tid == 0) { __threadfence(); set_flag(&gflag[t * 32 + g]); }
    }
  } else {
    // ---- B role: batch b, half h ----
    const int b = (blk - 32) >> 1, h = (blk - 32) & 1;
    float* raw = (float*)smem;
    float* aaw = raw + 64;
    const int s_i = tid >> 3, l8 = tid & 7;
    float sreg = (tid < 256) ? s0f[b * 512 + h * 256 + tid] : 0.f;
    for (int t = 0; t < 47; ++t) {
      if (tid < 32) wait_flag(&gflag[t * 32 + tid]);
      __syncthreads();
      __threadfence();
      // scores: energy[b,s] = v . tanh(sproj + encproj)  (dup across h)
      {
        float part = 0.f;
        const float* gp = gout + (size_t)b * 2048 + l8 * 64;
        const unsigned short* ep = epf + ((size_t)b * 64 + s_i) * 512 + l8 * 64;
        const float* vv = attnV + l8 * 64;
#pragma unroll
        for (int jc = 0; jc < 8; ++jc) {
          short8 e8 = *(const short8*)(ep + jc * 8);
          float4 g0 = *(const float4*)(gp + jc * 8);
          float4 g1 = *(const float4*)(gp + jc * 8 + 4);
          float4 v0 = *(const float4*)(vv + jc * 8);
          float4 v1 = *(const float4*)(vv + jc * 8 + 4);
          part += tanh_fast(g0.x + bf2f((unsigned short)e8[0])) * v0.x;
          part += tanh_fast(g0.y + bf2f((unsigned short)e8[1])) * v0.y;
          part += tanh_fast(g0.z + bf2f((unsigned short)e8[2])) * v0.z;
          part += tanh_fast(g0.w + bf2f((unsigned short)e8[3])) * v0.w;
          part += tanh_fast(g1.x + bf2f((unsigned short)e8[4])) * v1.x;
          part += tanh_fast(g1.y + bf2f((unsigned short)e8[5])) * v1.y;
          part += tanh_fast(g1.z + bf2f((unsigned short)e8[6])) * v1.z;
          part += tanh_fast(g1.w + bf2f((unsigned short)e8[7])) * v1.w;
        }
        part += __shfl_xor(part, 1);
        part += __shfl_xor(part, 2);
        part += __shfl_xor(part, 4);
        if (l8 == 0) raw[s_i] = part;
      }
      __syncthreads();
      if (tid < 64) {
        float x = raw[tid];
        float m = x;
#pragma unroll
        for (int k = 1; k < 64; k <<= 1) m = fmaxf(m, __shfl_xor(m, k));
        float e = __expf(x - m);
        float s = e;
#pragma unroll
        for (int k = 1; k < 64; k <<= 1) s += __shfl_xor(s, k);
        aaw[tid] = e * __builtin_amdgcn_rcpf(s);
      }
      __syncthreads();
      size_t zrow = ((size_t)t * 32 + b) * 2048;
      float c0 = 0.f, c1 = 0.f, s2v = 0.f;
      int j0 = 0, j1 = 0;
      if (tid < 256) {
        // gic accumulation + gates for d = h*256 + tid
        int d = h * 256 + tid;
        const unsigned short* e2 = EP2b + (size_t)b * 64 * 1536;
        float g0a = 0.f, g1a = 0.f, g2a = 0.f;
#pragma unroll 8
        for (int s2 = 0; s2 < 64; ++s2) {
          float a = aaw[s2];
          g0a += a * bf2f(e2[(size_t)s2 * 1536 + d]);
          g1a += a * bf2f(e2[(size_t)s2 * 1536 + 512 + d]);
          g2a += a * bf2f(e2[(size_t)s2 * 1536 + 1024 + d]);
        }
        const float* gie = Gie + ((size_t)t * 32 + b) * 1536;
        const float* gh = gout + (size_t)b * 2048;
        float rr = sigm_fast(gie[d] + g0a + gh[512 + d]);
        float zz = sigm_fast(gie[512 + d] + g1a + gh[1024 + d]);
        float nn = tanh_fast(gie[1024 + d] + g2a + rr * gh[1536 + d]);
        s2v = (1.f - zz) * nn + zz * sreg;
        sreg = s2v;
        sbf[((t + 1) & 1) * 16384 + b * 512 + d] = f2bf(s2v);
      } else {
        // context cols j0 = h*512 + tt, j1 = j0 + 256
        int tt = tid - 256;
        j0 = h * 512 + tt; j1 = j0 + 256;
        const unsigned short* eb = ebo + (size_t)b * 64 * 1024;
#pragma unroll 8
        for (int s2 = 0; s2 < 64; ++s2) {
          float a = aaw[s2];
          c0 += a * bf2f(eb[(size_t)s2 * 1024 + j0]);
          c1 += a * bf2f(eb[(size_t)s2 * 1024 + j1]);
        }
      }
      __syncthreads();
      if (tid == 0) { __threadfence(); set_flag(&sflag[t * 64 + b * 2 + h]); }
      // Zbf writes off the critical path
      if (tid < 256) {
        Zbf[zrow + h * 256 + tid] = f2bf(s2v);
      } else {
        Zbf[zrow + 512 + j0] = f2bf(c0);
        Zbf[zrow + 512 + j1] = f2bf(c1);
      }
    }
  }
}

extern "C" void kernel_launch(void* const* d_in, const int* in_sizes, int n_in,
                              void* d_out, int out_size, void* d_ws, size_t ws_size,
                              hipStream_t stream) {
  (void)in_sizes; (void)n_in; (void)out_size;
  const int* src = (const int*)d_in[0];
  const int* trg = (const int*)d_in[1];
  const float* emb = (const float*)d_in[2];
  const float* encf_Wih = (const float*)d_in[3];
  const float* encf_Whh = (const float*)d_in[4];
  const float* encf_bih = (const float*)d_in[5];
  const float* encf_bhh = (const float*)d_in[6];
  const float* encb_Wih = (const float*)d_in[7];
  const float* encb_Whh = (const float*)d_in[8];
  const float* encb_bih = (const float*)d_in[9];
  const float* encb_bhh = (const float*)d_in[10];
  const float* fc_W = (const float*)d_in[11];
  const float* fc_b = (const float*)d_in[12];
  const float* attn_W = (const float*)d_in[13];
  const float* attn_v = (const float*)d_in[14];
  const float* dec_Wih = (const float*)d_in[15];
  const float* dec_Whh = (const float*)d_in[16];
  const float* dec_bih = (const float*)d_in[17];
  const float* dec_bhh = (const float*)d_in[18];
  const float* out_W = (const float*)d_in[19];
  const float* out_b = (const float*)d_in[20];
  float* out = (float*)d_out;

  char* p = (char*)d_ws;
  size_t off = 0;
  auto alloc = [&](size_t bytes) {
    void* r = p + off;
    off = (off + bytes + 255) & ~(size_t)255;
    return r;
  };
  // flags: gflag[47*32] | sflag[47*64] | hflag[2*64*16]
  int* flg = (int*)alloc((47 * 32 + 47 * 64 + 2 * 64 * 16) * 4);
  int* gflag = flg;
  int* sflag = flg + 47 * 32;
  int* hflag = flg + 47 * 32 + 47 * 64;
  unsigned short* xbf = (unsigned short*)alloc((size_t)2048 * 512 * 2);
  unsigned short* ebf = (unsigned short*)alloc((size_t)1536 * 512 * 2);
  unsigned short* Zbf = (unsigned short*)alloc((size_t)1536 * 2048 * 2);
  float* Gif = (float*)alloc((size_t)2048 * 1536 * 4);
  float* Gib = (float*)alloc((size_t)2048 * 1536 * 4);
  float* Gie = (float*)alloc((size_t)1536 * 1536 * 4);
  unsigned short* ebo = (unsigned short*)alloc((size_t)2048 * 1024 * 2);
  unsigned short* epf = (unsigned short*)alloc((size_t)2048 * 512 * 2);
  unsigned short* EP2b = (unsigned short*)alloc((size_t)2048 * 1536 * 2);
  unsigned short* hbf = (unsigned short*)alloc((size_t)2 * 2 * 32 * 512 * 2);
  float* hcat = (float*)alloc((size_t)128 * 1024 * 4);
  float* s0raw = (float*)alloc((size_t)32 * 512 * 4);
  float* s0f = (float*)alloc((size_t)32 * 512 * 4);
  unsigned short* sbf = (unsigned short*)alloc((size_t)2 * 32 * 512 * 2);
  float* gout = (float*)alloc((size_t)32 * 2048 * 4);
  unsigned short* outWbf = (unsigned short*)alloc((size_t)32000 * 2048 * 2);
  const bool bigB = (off <= ws_size);

  hipMemsetAsync(flg, 0, (47 * 32 + 47 * 64 + 2 * 64 * 16) * 4, stream);
  hipMemsetAsync(hbf, 0, (size_t)2 * 2 * 32 * 512 * 2, stream);
  hipMemsetAsync(d_out, 0, (size_t)32 * 32000 * 4, stream);

  prep_gather<<<3584, 128, 0, stream>>>(src, trg, emb, xbf, ebf, Zbf);
  if (bigB)
    cvt_f32_bf16<<<4096, 256, 0, stream>>>(out_W, outWbf, (long long)32000 * 2048 / 4);

  gemm_kernel<true, false, false><<<dim3(16, 12), 256, 0, stream>>>(
      xbf, 512, encf_Wih, 512, 0, encf_bih, Gif, 1536, 512, 2048, 0);
  gemm_kernel<true, false, false><<<dim3(16, 12), 256, 0, stream>>>(
      xbf, 512, encb_Wih, 512, 0, encb_bih, Gib, 1536, 512, 2048, 0);
  gemm_kernel<true, false, false><<<dim3(12, 12), 256, 0, stream>>>(
      ebf, 512, dec_Wih, 1536, 0, dec_bih, Gie, 1536, 512, 1536, 0);

  enc_kernel<<<32, 512, 0, stream>>>(Gif, Gib, encf_Whh, encb_Whh, encf_bhh, encb_bhh,
                                     hbf, ebo, hcat, hflag);

  gemm_kernel<false, false, false><<<dim3(1, 4), 256, 0, stream>>>(
      hcat, 1024, fc_W, 1024, 0, fc_b, s0raw, 512, 1024, 32, 0);
  tanh_s0<<<32, 512, 0, stream>>>(s0raw, s0f, sbf);

  gemm_kernel<true, false, true><<<dim3(16, 4), 256, 0, stream>>>(
      ebo, 1024, attn_W, 1536, 512, nullptr, epf, 512, 1024, 2048, 0);
  gemm_kernel<true, false, true><<<dim3(16, 12), 256, 0, stream>>>(
      ebo, 1024, dec_Wih, 1536, 512, nullptr, EP2b, 1536, 1024, 2048, 0);

  dec_kernel<<<96, 512, 0, stream>>>(attn_W, dec_Whh, dec_bhh, attn_v, sbf, s0f,
                                     epf, ebo, EP2b, Gie, gout, Zbf, gflag, sflag);

  if (bigB)
    gemm_kernel<true, true, false><<<dim3(12, 250), 256, 0, stream>>>(
        Zbf, 2048, outWbf, 2048, 0, out_b, out, 32000, 2048, 1504, 32);
  else
    gemm_kernel<true, false, false><<<dim3(12, 250), 256, 0, stream>>>(
        Zbf, 2048, out_W, 2048, 0, out_b, out, 32000, 2048, 1504, 32);
}

// Round 7
// 2004.380 us; speedup vs baseline: 1.6446x; 1.6446x over previous
//
#include <hip/hip_runtime.h>
#include <stdint.h>
#include <stddef.h>

typedef __attribute__((ext_vector_type(8))) short short8;
typedef __attribute__((ext_vector_type(4))) float f32x4;

__device__ inline unsigned short f2bf(float f) {
  union { float f; uint32_t u; } v; v.f = f;
  uint32_t u = v.u;
  u += 0x7FFFu + ((u >> 16) & 1u);
  return (unsigned short)(u >> 16);
}
__device__ inline float bf2f(unsigned short h) {
  union { uint32_t u; float f; } v; v.u = ((uint32_t)h) << 16; return v.f;
}
__device__ inline short8 pack8(float4 a, float4 b) {
  short8 r;
  r[0] = (short)f2bf(a.x); r[1] = (short)f2bf(a.y);
  r[2] = (short)f2bf(a.z); r[3] = (short)f2bf(a.w);
  r[4] = (short)f2bf(b.x); r[5] = (short)f2bf(b.y);
  r[6] = (short)f2bf(b.z); r[7] = (short)f2bf(b.w);
  return r;
}
__device__ inline float tanh_fast(float x) {
  float xc = fminf(fmaxf(x, -9.f), 9.f);
  float e = __expf(2.f * xc);
  return (e - 1.f) * __builtin_amdgcn_rcpf(e + 1.f);
}
__device__ inline float sigm_fast(float x) {
  float xc = fminf(fmaxf(x, -30.f), 30.f);
  return __builtin_amdgcn_rcpf(1.f + __expf(-xc));
}

// Gather + bf16-convert embeddings.
__global__ __launch_bounds__(128) void prep_gather(
    const int* __restrict__ src, const int* __restrict__ trg,
    const float* __restrict__ emb,
    unsigned short* __restrict__ xbf, unsigned short* __restrict__ ebf,
    unsigned short* __restrict__ Zbf) {
  int r = blockIdx.x, tid = threadIdx.x;
  if (r < 2048) {
    int b = r & 31, s = r >> 5;
    int tok = src[b * 64 + s];
    const float* e = emb + (size_t)tok * 512;
    float4 v = *(const float4*)(e + tid * 4);
    unsigned short* dst = xbf + (size_t)r * 512 + tid * 4;
    dst[0] = f2bf(v.x); dst[1] = f2bf(v.y); dst[2] = f2bf(v.z); dst[3] = f2bf(v.w);
  } else {
    int rr = r - 2048;
    int t = rr >> 5, b = rr & 31;
    unsigned short* dst = ebf + (size_t)rr * 512 + tid * 4;
    if (t < 47) {
      int tok = trg[t * 32 + b];
      const float* e = emb + (size_t)tok * 512;
      float4 v = *(const float4*)(e + tid * 4);
      unsigned short q0 = f2bf(v.x), q1 = f2bf(v.y), q2 = f2bf(v.z), q3 = f2bf(v.w);
      dst[0] = q0; dst[1] = q1; dst[2] = q2; dst[3] = q3;
      unsigned short* zd = Zbf + (size_t)rr * 2048 + 1536 + tid * 4;
      zd[0] = q0; zd[1] = q1; zd[2] = q2; zd[3] = q3;
    } else {
      dst[0] = 0; dst[1] = 0; dst[2] = 0; dst[3] = 0;
    }
  }
}

__global__ __launch_bounds__(256) void cvt_f32_bf16(const float* __restrict__ src,
                                                    unsigned short* __restrict__ dst,
                                                    long long n4) {
  long long i = (long long)blockIdx.x * 256 + threadIdx.x;
  long long stride = (long long)gridDim.x * 256;
  for (; i < n4; i += stride) {
    float4 v = ((const float4*)src)[i];
    unsigned short* d = dst + i * 4;
    d[0] = f2bf(v.x); d[1] = f2bf(v.y); d[2] = f2bf(v.z); d[3] = f2bf(v.w);
  }
}

// Convert rows of a f32 matrix (leading dim srcld, 512 cols used) to bf16 [R][512].
__global__ __launch_bounds__(64) void cvt_rows(const float* __restrict__ src, int srcld,
                                               unsigned short* __restrict__ dst) {
  int r = blockIdx.x, c = threadIdx.x * 8;
  const float* s = src + (size_t)r * srcld + c;
  *(short8*)(dst + (size_t)r * 512 + c) = pack8(*(const float4*)s, *(const float4*)(s + 4));
}

// C[m,n] = sum_k A[m,k]*B[n,k] (+bias[n]). 128x128 tile, BK=32, 4 waves.
template <bool ABF, bool BBF, bool WBF>
__global__ __launch_bounds__(256) void gemm_kernel(
    const void* __restrict__ Av, int lda,
    const void* __restrict__ Bv, int ldb, int bco,
    const float* __restrict__ bias,
    void* __restrict__ Cv, int ldc,
    int K, int Mvalid, int row_off) {
  __shared__ __align__(16) unsigned short As[128 * 32];
  __shared__ __align__(16) unsigned short Bs[128 * 32];
  const int tid = threadIdx.x;
  const int m0 = blockIdx.x * 128, n0 = blockIdx.y * 128;
  const int w = tid >> 6, lane = tid & 63;
  const int wm = w >> 1, wn = w & 1;
  const int fr = lane & 15, fq = lane >> 4;
  f32x4 acc[4][4];
#pragma unroll
  for (int mi = 0; mi < 4; ++mi)
#pragma unroll
    for (int ni = 0; ni < 4; ++ni) acc[mi][ni] = (f32x4){0.f, 0.f, 0.f, 0.f};
  for (int k0 = 0; k0 < K; k0 += 32) {
#pragma unroll
    for (int p = 0; p < 2; ++p) {
      int idx = p * 256 + tid;
      int row = idx >> 2, seg = idx & 3;
      if (ABF) {
        const unsigned short* Ab = (const unsigned short*)Av;
        *(short8*)(As + row * 32 + seg * 8) =
            *(const short8*)(Ab + (size_t)(m0 + row) * lda + k0 + seg * 8);
      } else {
        const float* Af = (const float*)Av;
        const float* ap = Af + (size_t)(m0 + row) * lda + k0 + seg * 8;
        *(short8*)(As + row * 32 + seg * 8) = pack8(*(const float4*)ap, *(const float4*)(ap + 4));
      }
      if (BBF) {
        const unsigned short* Bb = (const unsigned short*)Bv;
        *(short8*)(Bs + row * 32 + seg * 8) =
            *(const short8*)(Bb + (size_t)(n0 + row) * ldb + bco + k0 + seg * 8);
      } else {
        const float* Bf = (const float*)Bv;
        const float* bp = Bf + (size_t)(n0 + row) * ldb + bco + k0 + seg * 8;
        *(short8*)(Bs + row * 32 + seg * 8) = pack8(*(const float4*)bp, *(const float4*)(bp + 4));
      }
    }
    __syncthreads();
    short8 af[4], bfr[4];
#pragma unroll
    for (int mi = 0; mi < 4; ++mi)
      af[mi] = *(const short8*)(As + (wm * 64 + mi * 16 + fr) * 32 + fq * 8);
#pragma unroll
    for (int ni = 0; ni < 4; ++ni)
      bfr[ni] = *(const short8*)(Bs + (wn * 64 + ni * 16 + fr) * 32 + fq * 8);
#pragma unroll
    for (int mi = 0; mi < 4; ++mi)
#pragma unroll
      for (int ni = 0; ni < 4; ++ni)
        acc[mi][ni] = __builtin_amdgcn_mfma_f32_16x16x32_bf16(af[mi], bfr[ni], acc[mi][ni], 0, 0, 0);
    __syncthreads();
  }
#pragma unroll
  for (int mi = 0; mi < 4; ++mi)
#pragma unroll
    for (int ni = 0; ni < 4; ++ni) {
      int col = n0 + wn * 64 + ni * 16 + fr;
      float bv = bias ? bias[col] : 0.f;
#pragma unroll
      for (int j = 0; j < 4; ++j) {
        int rowm = m0 + wm * 64 + mi * 16 + fq * 4 + j;
        if (rowm < Mvalid) {
          float val = acc[mi][ni][j] + bv;
          if (WBF)
            ((unsigned short*)Cv)[(size_t)(rowm + row_off) * ldc + col] = f2bf(val);
          else
            ((float*)Cv)[(size_t)(rowm + row_off) * ldc + col] = val;
        }
      }
    }
}

// One encoder GRU step, both directions. 32 blocks: dir=blk>>4, 32-d slice.
// Sequencing across steps = kernel boundary (runtime release/acquire).
__global__ __launch_bounds__(512) void enc_step(
    const float* __restrict__ Gif, const float* __restrict__ Gib,
    const unsigned short* __restrict__ whFbf, const unsigned short* __restrict__ whBbf,
    const float* __restrict__ bhhF, const float* __restrict__ bhhB,
    unsigned short* __restrict__ hbf,   // [dir][2][32][512] bf16
    float* __restrict__ hf32,           // [dir][2][32][512] f32
    unsigned short* __restrict__ ebo,   // [b][s][1024] bf16
    float* __restrict__ hcat,           // [b][1024] f32
    int t) {
  const int blk = blockIdx.x, tid = threadIdx.x;
  const int dir = blk >> 4, slice = blk & 15, D0 = slice * 32;
  const unsigned short* Wbf = dir ? whBbf : whFbf;
  const float* Gi = dir ? Gib : Gif;
  const float* bhh = dir ? bhhB : bhhF;
  __shared__ __align__(16) unsigned short hlds[32 * 520];
  __shared__ __align__(16) float gl[96 * 33];
  const unsigned short* hb = hbf + dir * 32768 + (t & 1) * 16384;
  for (int c = tid; c < 32 * 64; c += 512) {
    int r = c >> 6, seg = c & 63;
    *(short8*)(hlds + r * 520 + seg * 8) = *(const short8*)(hb + r * 512 + seg * 8);
  }
  __syncthreads();
  const int w = tid >> 6, lane = tid & 63, fr = lane & 15, fq = lane >> 4;
  if (w < 6) {
    int row = w * 16 + fr;
    int gr = (row >> 5) * 512 + D0 + (row & 31);
    const unsigned short* wrow = Wbf + (size_t)gr * 512;
    f32x4 acc0 = {0.f, 0.f, 0.f, 0.f}, acc1 = {0.f, 0.f, 0.f, 0.f};
#pragma unroll
    for (int k0 = 0; k0 < 512; k0 += 32) {
      short8 bq = *(const short8*)(wrow + k0 + fq * 8);
      short8 a0 = *(const short8*)(hlds + fr * 520 + k0 + fq * 8);
      short8 a1 = *(const short8*)(hlds + (16 + fr) * 520 + k0 + fq * 8);
      acc0 = __builtin_amdgcn_mfma_f32_16x16x32_bf16(a0, bq, acc0, 0, 0, 0);
      acc1 = __builtin_amdgcn_mfma_f32_16x16x32_bf16(a1, bq, acc1, 0, 0, 0);
    }
#pragma unroll
    for (int j = 0; j < 4; ++j) {
      gl[row * 33 + fq * 4 + j] = acc0[j];
      gl[row * 33 + 16 + fq * 4 + j] = acc1[j];
    }
  }
  __syncthreads();
  const int srow = dir ? 63 - t : t;
  unsigned short* hnb = hbf + dir * 32768 + ((t + 1) & 1) * 16384;
  const float* hcur = hf32 + dir * 32768 + (t & 1) * 16384;
  float* hnf = hf32 + dir * 32768 + ((t + 1) & 1) * 16384;
#pragma unroll
  for (int rep = 0; rep < 2; ++rep) {
    int idx = rep * 512 + tid, b = idx >> 5, dl = idx & 31, d = D0 + dl;
    float ar = gl[dl * 33 + b] + bhh[d];
    float az = gl[(32 + dl) * 33 + b] + bhh[512 + d];
    float an = gl[(64 + dl) * 33 + b] + bhh[1024 + d];
    const float* gi = Gi + ((size_t)srow * 32 + b) * 1536;
    float r = sigm_fast(gi[d] + ar);
    float z = sigm_fast(gi[512 + d] + az);
    float n = tanh_fast(gi[1024 + d] + r * an);
    float h2 = (1.f - z) * n + z * hcur[b * 512 + d];
    hnb[b * 512 + d] = f2bf(h2);
    hnf[b * 512 + d] = h2;
    ebo[((size_t)b * 64 + srow) * 1024 + (size_t)dir * 512 + d] = f2bf(h2);
    if (t == 63) hcat[(size_t)b * 1024 + (size_t)dir * 512 + d] = h2;
  }
}

__global__ __launch_bounds__(512) void tanh_s0(const float* __restrict__ s0raw,
                                               float* __restrict__ sf32,
                                               unsigned short* __restrict__ sbf) {
  int idx = blockIdx.x * 512 + threadIdx.x;
  float v = tanhf(s0raw[idx]);
  sf32[idx] = v;
  sbf[idx] = f2bf(v);
}

// Decoder step part 1: gout[b][n] = s_t[b] . Wcat[n] (+decBhh for n>=512).
// Wcat rows 0..511 = attn_W[:, :512]; rows 512..2047 = dec_Whh.
__global__ __launch_bounds__(512) void dec_proj(
    const unsigned short* __restrict__ Wcat, const float* __restrict__ decBhh,
    const unsigned short* __restrict__ sbf, float* __restrict__ gout, int t) {
  const int g = blockIdx.x, tid = threadIdx.x;
  __shared__ __align__(16) unsigned short slds[32 * 520];
  const unsigned short* sb = sbf + (t & 1) * 16384;
  for (int c = tid; c < 32 * 64; c += 512) {
    int r = c >> 6, seg = c & 63;
    *(short8*)(slds + r * 520 + seg * 8) = *(const short8*)(sb + r * 512 + seg * 8);
  }
  __syncthreads();
  const int w = tid >> 6, lane = tid & 63, fr = lane & 15, fq = lane >> 4;
  const int mt = w >> 2, nt = w & 3;
  int rc = g * 64 + nt * 16 + fr;
  const unsigned short* wrow = Wcat + (size_t)rc * 512;
  f32x4 acc = {0.f, 0.f, 0.f, 0.f};
#pragma unroll
  for (int k0 = 0; k0 < 512; k0 += 32) {
    short8 a = *(const short8*)(slds + (mt * 16 + fr) * 520 + k0 + fq * 8);
    short8 bq = *(const short8*)(wrow + k0 + fq * 8);
    acc = __builtin_amdgcn_mfma_f32_16x16x32_bf16(a, bq, acc, 0, 0, 0);
  }
  float bv = rc < 512 ? 0.f : decBhh[rc - 512];
#pragma unroll
  for (int j = 0; j < 4; ++j)
    gout[(size_t)(mt * 16 + fq * 4 + j) * 2048 + rc] = acc[j] + bv;
}

// Decoder step part 2: scores, softmax, context, gic, gates. One block per batch.
__global__ __launch_bounds__(512) void dec_attn(
    const float* __restrict__ attnV,
    const unsigned short* __restrict__ epf, const unsigned short* __restrict__ ebo,
    const unsigned short* __restrict__ EP2b, const float* __restrict__ Gie,
    const float* __restrict__ gout,
    unsigned short* __restrict__ sbf, float* __restrict__ sf32,
    unsigned short* __restrict__ Zbf, int t) {
  const int b = blockIdx.x, tid = threadIdx.x;
  __shared__ __align__(16) float gout_f[2048];
  __shared__ float raw[64], aaw[64];
  __shared__ float vlds[512];
  vlds[tid] = attnV[tid];
  *(float4*)(gout_f + tid * 4) = *(const float4*)(gout + (size_t)b * 2048 + tid * 4);
  __syncthreads();
  const int s_i = tid >> 3, l8 = tid & 7;
  // scores: energy[b,s] = v . tanh(sproj + encproj)
  {
    float part = 0.f;
    const float* gp = gout_f + l8 * 64;
    const unsigned short* ep = epf + ((size_t)b * 64 + s_i) * 512 + l8 * 64;
    const float* vv = vlds + l8 * 64;
#pragma unroll
    for (int jc = 0; jc < 8; ++jc) {
      short8 e8 = *(const short8*)(ep + jc * 8);
      float4 g0 = *(const float4*)(gp + jc * 8);
      float4 g1 = *(const float4*)(gp + jc * 8 + 4);
      float4 v0 = *(const float4*)(vv + jc * 8);
      float4 v1 = *(const float4*)(vv + jc * 8 + 4);
      part += tanh_fast(g0.x + bf2f((unsigned short)e8[0])) * v0.x;
      part += tanh_fast(g0.y + bf2f((unsigned short)e8[1])) * v0.y;
      part += tanh_fast(g0.z + bf2f((unsigned short)e8[2])) * v0.z;
      part += tanh_fast(g0.w + bf2f((unsigned short)e8[3])) * v0.w;
      part += tanh_fast(g1.x + bf2f((unsigned short)e8[4])) * v1.x;
      part += tanh_fast(g1.y + bf2f((unsigned short)e8[5])) * v1.y;
      part += tanh_fast(g1.z + bf2f((unsigned short)e8[6])) * v1.z;
      part += tanh_fast(g1.w + bf2f((unsigned short)e8[7])) * v1.w;
    }
    part += __shfl_xor(part, 1);
    part += __shfl_xor(part, 2);
    part += __shfl_xor(part, 4);
    if (l8 == 0) raw[s_i] = part;
  }
  __syncthreads();
  if (tid < 64) {
    float x = raw[tid];
    float m = x;
#pragma unroll
    for (int k = 1; k < 64; k <<= 1) m = fmaxf(m, __shfl_xor(m, k));
    float e = __expf(x - m);
    float s = e;
#pragma unroll
    for (int k = 1; k < 64; k <<= 1) s += __shfl_xor(s, k);
    aaw[tid] = e * __builtin_amdgcn_rcpf(s);
  }
  __syncthreads();
  // context (2 cols) + gic (3 rows) + gates for d = tid
  float c0 = 0.f, c1 = 0.f, g0a = 0.f, g1a = 0.f, g2a = 0.f;
  {
    const unsigned short* eb = ebo + (size_t)b * 64 * 1024 + tid;
    const unsigned short* e2 = EP2b + (size_t)b * 64 * 1536 + tid;
#pragma unroll 8
    for (int s2 = 0; s2 < 64; ++s2) {
      float a = aaw[s2];
      c0 += a * bf2f(eb[(size_t)s2 * 1024]);
      c1 += a * bf2f(eb[(size_t)s2 * 1024 + 512]);
      g0a += a * bf2f(e2[(size_t)s2 * 1536]);
      g1a += a * bf2f(e2[(size_t)s2 * 1536 + 512]);
      g2a += a * bf2f(e2[(size_t)s2 * 1536 + 1024]);
    }
  }
  const float* gie = Gie + ((size_t)t * 32 + b) * 1536;
  float sprev = sf32[(t & 1) * 16384 + b * 512 + tid];
  float rr = sigm_fast(gie[tid] + g0a + gout_f[512 + tid]);
  float zz = sigm_fast(gie[512 + tid] + g1a + gout_f[1024 + tid]);
  float nn = tanh_fast(gie[1024 + tid] + g2a + rr * gout_f[1536 + tid]);
  float s2v = (1.f - zz) * nn + zz * sprev;
  sbf[((t + 1) & 1) * 16384 + b * 512 + tid] = f2bf(s2v);
  sf32[((t + 1) & 1) * 16384 + b * 512 + tid] = s2v;
  size_t zrow = ((size_t)t * 32 + b) * 2048;
  Zbf[zrow + tid] = f2bf(s2v);
  Zbf[zrow + 512 + tid] = f2bf(c0);
  Zbf[zrow + 1024 + tid] = f2bf(c1);
}

extern "C" void kernel_launch(void* const* d_in, const int* in_sizes, int n_in,
                              void* d_out, int out_size, void* d_ws, size_t ws_size,
                              hipStream_t stream) {
  (void)in_sizes; (void)n_in; (void)out_size;
  const int* src = (const int*)d_in[0];
  const int* trg = (const int*)d_in[1];
  const float* emb = (const float*)d_in[2];
  const float* encf_Wih = (const float*)d_in[3];
  const float* encf_Whh = (const float*)d_in[4];
  const float* encf_bih = (const float*)d_in[5];
  const float* encf_bhh = (const float*)d_in[6];
  const float* encb_Wih = (const float*)d_in[7];
  const float* encb_Whh = (const float*)d_in[8];
  const float* encb_bih = (const float*)d_in[9];
  const float* encb_bhh = (const float*)d_in[10];
  const float* fc_W = (const float*)d_in[11];
  const float* fc_b = (const float*)d_in[12];
  const float* attn_W = (const float*)d_in[13];
  const float* attn_v = (const float*)d_in[14];
  const float* dec_Wih = (const float*)d_in[15];
  const float* dec_Whh = (const float*)d_in[16];
  const float* dec_bih = (const float*)d_in[17];
  const float* dec_bhh = (const float*)d_in[18];
  const float* out_W = (const float*)d_in[19];
  const float* out_b = (const float*)d_in[20];
  float* out = (float*)d_out;

  char* p = (char*)d_ws;
  size_t off = 0;
  auto alloc = [&](size_t bytes) {
    void* r = p + off;
    off = (off + bytes + 255) & ~(size_t)255;
    return r;
  };
  unsigned short* xbf = (unsigned short*)alloc((size_t)2048 * 512 * 2);
  unsigned short* ebf = (unsigned short*)alloc((size_t)1536 * 512 * 2);
  unsigned short* Zbf = (unsigned short*)alloc((size_t)1536 * 2048 * 2);
  float* Gif = (float*)alloc((size_t)2048 * 1536 * 4);
  float* Gib = (float*)alloc((size_t)2048 * 1536 * 4);
  float* Gie = (float*)alloc((size_t)1536 * 1536 * 4);
  unsigned short* ebo = (unsigned short*)alloc((size_t)2048 * 1024 * 2);
  unsigned short* epf = (unsigned short*)alloc((size_t)2048 * 512 * 2);
  unsigned short* EP2b = (unsigned short*)alloc((size_t)2048 * 1536 * 2);
  unsigned short* whFbf = (unsigned short*)alloc((size_t)1536 * 512 * 2);
  unsigned short* whBbf = (unsigned short*)alloc((size_t)1536 * 512 * 2);
  unsigned short* Wcat = (unsigned short*)alloc((size_t)2048 * 512 * 2);
  unsigned short* hbf = (unsigned short*)alloc((size_t)2 * 2 * 32 * 512 * 2);
  float* hf32 = (float*)alloc((size_t)2 * 2 * 32 * 512 * 4);
  float* hcat = (float*)alloc((size_t)32 * 1024 * 4);
  float* s0raw = (float*)alloc((size_t)32 * 512 * 4);
  unsigned short* sbf = (unsigned short*)alloc((size_t)2 * 32 * 512 * 2);
  float* sf32 = (float*)alloc((size_t)2 * 32 * 512 * 4);
  float* gout = (float*)alloc((size_t)32 * 2048 * 4);
  unsigned short* outWbf = (unsigned short*)alloc((size_t)32000 * 2048 * 2);
  const bool bigB = (off <= ws_size);

  hipMemsetAsync(hbf, 0, (size_t)2 * 2 * 32 * 512 * 2, stream);
  hipMemsetAsync(hf32, 0, (size_t)2 * 2 * 32 * 512 * 4, stream);
  hipMemsetAsync(d_out, 0, (size_t)32 * 32000 * 4, stream);

  prep_gather<<<3584, 128, 0, stream>>>(src, trg, emb, xbf, ebf, Zbf);
  if (bigB)
    cvt_f32_bf16<<<4096, 256, 0, stream>>>(out_W, outWbf, (long long)32000 * 2048 / 4);
  cvt_rows<<<1536, 64, 0, stream>>>(encf_Whh, 512, whFbf);
  cvt_rows<<<1536, 64, 0, stream>>>(encb_Whh, 512, whBbf);
  cvt_rows<<<512, 64, 0, stream>>>(attn_W, 1536, Wcat);              // sproj part
  cvt_rows<<<1536, 64, 0, stream>>>(dec_Whh, 512, Wcat + (size_t)512 * 512);

  gemm_kernel<true, false, false><<<dim3(16, 12), 256, 0, stream>>>(
      xbf, 512, encf_Wih, 512, 0, encf_bih, Gif, 1536, 512, 2048, 0);
  gemm_kernel<true, false, false><<<dim3(16, 12), 256, 0, stream>>>(
      xbf, 512, encb_Wih, 512, 0, encb_bih, Gib, 1536, 512, 2048, 0);
  gemm_kernel<true, false, false><<<dim3(12, 12), 256, 0, stream>>>(
      ebf, 512, dec_Wih, 1536, 0, dec_bih, Gie, 1536, 512, 1536, 0);

  for (int t = 0; t < 64; ++t)
    enc_step<<<32, 512, 0, stream>>>(Gif, Gib, whFbf, whBbf, encf_bhh, encb_bhh,
                                     hbf, hf32, ebo, hcat, t);

  gemm_kernel<false, false, false><<<dim3(1, 4), 256, 0, stream>>>(
      hcat, 1024, fc_W, 1024, 0, fc_b, s0raw, 512, 1024, 32, 0);
  tanh_s0<<<32, 512, 0, stream>>>(s0raw, sf32, sbf);

  gemm_kernel<true, false, true><<<dim3(16, 4), 256, 0, stream>>>(
      ebo, 1024, attn_W, 1536, 512, nullptr, epf, 512, 1024, 2048, 0);
  gemm_kernel<true, false, true><<<dim3(16, 12), 256, 0, stream>>>(
      ebo, 1024, dec_Wih, 1536, 512, nullptr, EP2b, 1536, 1024, 2048, 0);

  for (int t = 0; t < 47; ++t) {
    dec_proj<<<32, 512, 0, stream>>>(Wcat, dec_bhh, sbf, gout, t);
    dec_attn<<<32, 512, 0, stream>>>(attn_v, epf, ebo, EP2b, Gie, gout,
                                     sbf, sf32, Zbf, t);
  }

  if (bigB)
    gemm_kernel<true, true, false><<<dim3(12, 250), 256, 0, stream>>>(
        Zbf, 2048, outWbf, 2048, 0, out_b, out, 32000, 2048, 1504, 32);
  else
    gemm_kernel<true, false, false><<<dim3(12, 250), 256, 0, stream>>>(
        Zbf, 2048, out_W, 2048, 0, out_b, out, 32000, 2048, 1504, 32);
}

// Round 8
// 1981.532 us; speedup vs baseline: 1.6635x; 1.0115x over previous
//
#include <hip/hip_runtime.h>
#include <stdint.h>
#include <stddef.h>

typedef __attribute__((ext_vector_type(8))) short short8;
typedef __attribute__((ext_vector_type(4))) float f32x4;
typedef unsigned int u32;

__device__ inline unsigned short f2bf(float f) {
  union { float f; uint32_t u; } v; v.f = f;
  uint32_t u = v.u;
  u += 0x7FFFu + ((u >> 16) & 1u);
  return (unsigned short)(u >> 16);
}
__device__ inline float bf2f(unsigned short h) {
  union { uint32_t u; float f; } v; v.u = ((uint32_t)h) << 16; return v.f;
}
__device__ inline short8 pack8(float4 a, float4 b) {
  short8 r;
  r[0] = (short)f2bf(a.x); r[1] = (short)f2bf(a.y);
  r[2] = (short)f2bf(a.z); r[3] = (short)f2bf(a.w);
  r[4] = (short)f2bf(b.x); r[5] = (short)f2bf(b.y);
  r[6] = (short)f2bf(b.z); r[7] = (short)f2bf(b.w);
  return r;
}
__device__ inline float tanh_fast(float x) {
  float xc = fminf(fmaxf(x, -9.f), 9.f);
  float e = __expf(2.f * xc);
  return (e - 1.f) * __builtin_amdgcn_rcpf(e + 1.f);
}
__device__ inline float sigm_fast(float x) {
  float xc = fminf(fmaxf(x, -30.f), 30.f);
  return __builtin_amdgcn_rcpf(1.f + __expf(-xc));
}
// async global->LDS, 16 bytes per lane (wave-uniform LDS base + lane*16)
__device__ inline void gl_lds16(const unsigned short* g, unsigned short* l) {
  __builtin_amdgcn_global_load_lds(
      (const __attribute__((address_space(1))) u32*)g,
      (__attribute__((address_space(3))) u32*)l, 16, 0, 0);
}

// Gather + bf16-convert embeddings.
__global__ __launch_bounds__(128) void prep_gather(
    const int* __restrict__ src, const int* __restrict__ trg,
    const float* __restrict__ emb,
    unsigned short* __restrict__ xbf, unsigned short* __restrict__ ebf,
    unsigned short* __restrict__ Zbf) {
  int r = blockIdx.x, tid = threadIdx.x;
  if (r < 2048) {
    int b = r & 31, s = r >> 5;
    int tok = src[b * 64 + s];
    const float* e = emb + (size_t)tok * 512;
    float4 v = *(const float4*)(e + tid * 4);
    unsigned short* dst = xbf + (size_t)r * 512 + tid * 4;
    dst[0] = f2bf(v.x); dst[1] = f2bf(v.y); dst[2] = f2bf(v.z); dst[3] = f2bf(v.w);
  } else {
    int rr = r - 2048;
    int t = rr >> 5, b = rr & 31;
    unsigned short* dst = ebf + (size_t)rr * 512 + tid * 4;
    if (t < 47) {
      int tok = trg[t * 32 + b];
      const float* e = emb + (size_t)tok * 512;
      float4 v = *(const float4*)(e + tid * 4);
      unsigned short q0 = f2bf(v.x), q1 = f2bf(v.y), q2 = f2bf(v.z), q3 = f2bf(v.w);
      dst[0] = q0; dst[1] = q1; dst[2] = q2; dst[3] = q3;
      unsigned short* zd = Zbf + (size_t)rr * 2048 + 1536 + tid * 4;
      zd[0] = q0; zd[1] = q1; zd[2] = q2; zd[3] = q3;
    } else {
      dst[0] = 0; dst[1] = 0; dst[2] = 0; dst[3] = 0;
    }
  }
}

__global__ __launch_bounds__(256) void cvt_f32_bf16(const float* __restrict__ src,
                                                    unsigned short* __restrict__ dst,
                                                    long long n4) {
  long long i = (long long)blockIdx.x * 256 + threadIdx.x;
  long long stride = (long long)gridDim.x * 256;
  for (; i < n4; i += stride) {
    float4 v = ((const float4*)src)[i];
    unsigned short* d = dst + i * 4;
    d[0] = f2bf(v.x); d[1] = f2bf(v.y); d[2] = f2bf(v.z); d[3] = f2bf(v.w);
  }
}

// Convert rows of a f32 matrix (leading dim srcld, 512 cols used) to bf16 [R][512].
__global__ __launch_bounds__(64) void cvt_rows(const float* __restrict__ src, int srcld,
                                               unsigned short* __restrict__ dst) {
  int r = blockIdx.x, c = threadIdx.x * 8;
  const float* s = src + (size_t)r * srcld + c;
  *(short8*)(dst + (size_t)r * 512 + c) = pack8(*(const float4*)s, *(const float4*)(s + 4));
}

// C[m,n] = sum_k A[m,k]*B[n,k] (+bias[n]). 128x128 tile, BK=32, 4 waves.
template <bool ABF, bool BBF, bool WBF>
__global__ __launch_bounds__(256) void gemm_kernel(
    const void* __restrict__ Av, int lda,
    const void* __restrict__ Bv, int ldb, int bco,
    const float* __restrict__ bias,
    void* __restrict__ Cv, int ldc,
    int K, int Mvalid, int row_off) {
  __shared__ __align__(16) unsigned short As[128 * 32];
  __shared__ __align__(16) unsigned short Bs[128 * 32];
  const int tid = threadIdx.x;
  const int m0 = blockIdx.x * 128, n0 = blockIdx.y * 128;
  const int w = tid >> 6, lane = tid & 63;
  const int wm = w >> 1, wn = w & 1;
  const int fr = lane & 15, fq = lane >> 4;
  f32x4 acc[4][4];
#pragma unroll
  for (int mi = 0; mi < 4; ++mi)
#pragma unroll
    for (int ni = 0; ni < 4; ++ni) acc[mi][ni] = (f32x4){0.f, 0.f, 0.f, 0.f};
  for (int k0 = 0; k0 < K; k0 += 32) {
#pragma unroll
    for (int p = 0; p < 2; ++p) {
      int idx = p * 256 + tid;
      int row = idx >> 2, seg = idx & 3;
      if (ABF) {
        const unsigned short* Ab = (const unsigned short*)Av;
        *(short8*)(As + row * 32 + seg * 8) =
            *(const short8*)(Ab + (size_t)(m0 + row) * lda + k0 + seg * 8);
      } else {
        const float* Af = (const float*)Av;
        const float* ap = Af + (size_t)(m0 + row) * lda + k0 + seg * 8;
        *(short8*)(As + row * 32 + seg * 8) = pack8(*(const float4*)ap, *(const float4*)(ap + 4));
      }
      if (BBF) {
        const unsigned short* Bb = (const unsigned short*)Bv;
        *(short8*)(Bs + row * 32 + seg * 8) =
            *(const short8*)(Bb + (size_t)(n0 + row) * ldb + bco + k0 + seg * 8);
      } else {
        const float* Bf = (const float*)Bv;
        const float* bp = Bf + (size_t)(n0 + row) * ldb + bco + k0 + seg * 8;
        *(short8*)(Bs + row * 32 + seg * 8) = pack8(*(const float4*)bp, *(const float4*)(bp + 4));
      }
    }
    __syncthreads();
    short8 af[4], bfr[4];
#pragma unroll
    for (int mi = 0; mi < 4; ++mi)
      af[mi] = *(const short8*)(As + (wm * 64 + mi * 16 + fr) * 32 + fq * 8);
#pragma unroll
    for (int ni = 0; ni < 4; ++ni)
      bfr[ni] = *(const short8*)(Bs + (wn * 64 + ni * 16 + fr) * 32 + fq * 8);
#pragma unroll
    for (int mi = 0; mi < 4; ++mi)
#pragma unroll
      for (int ni = 0; ni < 4; ++ni)
        acc[mi][ni] = __builtin_amdgcn_mfma_f32_16x16x32_bf16(af[mi], bfr[ni], acc[mi][ni], 0, 0, 0);
    __syncthreads();
  }
#pragma unroll
  for (int mi = 0; mi < 4; ++mi)
#pragma unroll
    for (int ni = 0; ni < 4; ++ni) {
      int col = n0 + wn * 64 + ni * 16 + fr;
      float bv = bias ? bias[col] : 0.f;
#pragma unroll
      for (int j = 0; j < 4; ++j) {
        int rowm = m0 + wm * 64 + mi * 16 + fq * 4 + j;
        if (rowm < Mvalid) {
          float val = acc[mi][ni][j] + bv;
          if (WBF)
            ((unsigned short*)Cv)[(size_t)(rowm + row_off) * ldc + col] = f2bf(val);
          else
            ((float*)Cv)[(size_t)(rowm + row_off) * ldc + col] = val;
        }
      }
    }
}

// Big output GEMM: both operands bf16, global_load_lds staging, XCD-swizzled
// 1D grid (m-fastest within an XCD's contiguous n-range).
__global__ __launch_bounds__(256) void gemm_big(
    const unsigned short* __restrict__ A, int lda,   // [1536][2048] bf16
    const unsigned short* __restrict__ B, int ldb,   // [32000][2048] bf16
    const float* __restrict__ bias,
    float* __restrict__ C, int ldc,
    int K, int Mvalid, int row_off) {
  __shared__ __align__(16) unsigned short As[128 * 32];
  __shared__ __align__(16) unsigned short Bs[128 * 32];
  const int tid = threadIdx.x;
  // bijective XCD swizzle: 3000 blocks = 8 XCDs x 375
  int wg = blockIdx.x;
  wg = (wg & 7) * 375 + (wg >> 3);
  const int m0 = (wg % 12) * 128, n0 = (wg / 12) * 128;
  const int w = tid >> 6, lane = tid & 63;
  const int wm = w >> 1, wn = w & 1;
  const int fr = lane & 15, fq = lane >> 4;
  const int srow = lane >> 2, sseg = lane & 3;  // staging: 16 rows/wave-load
  f32x4 acc[4][4];
#pragma unroll
  for (int mi = 0; mi < 4; ++mi)
#pragma unroll
    for (int ni = 0; ni < 4; ++ni) acc[mi][ni] = (f32x4){0.f, 0.f, 0.f, 0.f};
  for (int k0 = 0; k0 < K; k0 += 32) {
    // each wave stages 32 rows of A and 32 rows of B (2 x 1KB chunks each)
#pragma unroll
    for (int c = 0; c < 2; ++c) {
      int row = w * 32 + c * 16 + srow;
      gl_lds16(A + (size_t)(m0 + row) * lda + k0 + sseg * 8, As + row * 32);
      gl_lds16(B + (size_t)(n0 + row) * ldb + k0 + sseg * 8, Bs + row * 32);
    }
    __syncthreads();
    short8 af[4], bfr[4];
#pragma unroll
    for (int mi = 0; mi < 4; ++mi)
      af[mi] = *(const short8*)(As + (wm * 64 + mi * 16 + fr) * 32 + fq * 8);
#pragma unroll
    for (int ni = 0; ni < 4; ++ni)
      bfr[ni] = *(const short8*)(Bs + (wn * 64 + ni * 16 + fr) * 32 + fq * 8);
#pragma unroll
    for (int mi = 0; mi < 4; ++mi)
#pragma unroll
      for (int ni = 0; ni < 4; ++ni)
        acc[mi][ni] = __builtin_amdgcn_mfma_f32_16x16x32_bf16(af[mi], bfr[ni], acc[mi][ni], 0, 0, 0);
    __syncthreads();
  }
#pragma unroll
  for (int mi = 0; mi < 4; ++mi)
#pragma unroll
    for (int ni = 0; ni < 4; ++ni) {
      int col = n0 + wn * 64 + ni * 16 + fr;
      float bv = bias[col];
#pragma unroll
      for (int j = 0; j < 4; ++j) {
        int rowm = m0 + wm * 64 + mi * 16 + fq * 4 + j;
        if (rowm < Mvalid) C[(size_t)(rowm + row_off) * ldc + col] = acc[mi][ni][j] + bv;
      }
    }
}

// One encoder GRU step, both directions. Blocks 0..31: dir=blk>>4, 32-d slice.
// Blocks 32..231: piggyback out_W f32->bf16 conversion (idle-CU work).
__global__ __launch_bounds__(512) void enc_step(
    const float* __restrict__ Gif, const float* __restrict__ Gib,
    const unsigned short* __restrict__ whFbf, const unsigned short* __restrict__ whBbf,
    const float* __restrict__ bhhF, const float* __restrict__ bhhB,
    unsigned short* __restrict__ hbf,   // [dir][2][32][512] bf16
    float* __restrict__ hf32,           // [dir][2][32][512] f32
    unsigned short* __restrict__ ebo,   // [b][s][1024] bf16
    float* __restrict__ hcat,           // [b][1024] f32
    const float* __restrict__ outW, unsigned short* __restrict__ outWbf, int nCvt,
    int t) {
  const int blk = blockIdx.x, tid = threadIdx.x;
  if (blk >= 32) {
    if (blk - 32 < nCvt) {
      // convert 5120 f32 (1280 float4) of out_W
      size_t base4 = ((size_t)t * nCvt + (blk - 32)) * 1280;
      for (int i = tid; i < 1280; i += 512) {
        float4 v = ((const float4*)outW)[base4 + i];
        unsigned short* d = outWbf + (base4 + i) * 4;
        d[0] = f2bf(v.x); d[1] = f2bf(v.y); d[2] = f2bf(v.z); d[3] = f2bf(v.w);
      }
    }
    return;
  }
  const int dir = blk >> 4, slice = blk & 15, D0 = slice * 32;
  const unsigned short* Wbf = dir ? whBbf : whFbf;
  const float* Gi = dir ? Gib : Gif;
  const float* bhh = dir ? bhhB : bhhF;
  __shared__ __align__(16) unsigned short hlds[32 * 520];
  __shared__ __align__(16) float gl[96 * 33];
  const unsigned short* hb = hbf + dir * 32768 + (t & 1) * 16384;
  for (int c = tid; c < 32 * 64; c += 512) {
    int r = c >> 6, seg = c & 63;
    *(short8*)(hlds + r * 520 + seg * 8) = *(const short8*)(hb + r * 512 + seg * 8);
  }
  __syncthreads();
  const int w = tid >> 6, lane = tid & 63, fr = lane & 15, fq = lane >> 4;
  if (w < 6) {
    int row = w * 16 + fr;
    int gr = (row >> 5) * 512 + D0 + (row & 31);
    const unsigned short* wrow = Wbf + (size_t)gr * 512;
    f32x4 acc0 = {0.f, 0.f, 0.f, 0.f}, acc1 = {0.f, 0.f, 0.f, 0.f};
#pragma unroll
    for (int k0 = 0; k0 < 512; k0 += 32) {
      short8 bq = *(const short8*)(wrow + k0 + fq * 8);
      short8 a0 = *(const short8*)(hlds + fr * 520 + k0 + fq * 8);
      short8 a1 = *(const short8*)(hlds + (16 + fr) * 520 + k0 + fq * 8);
      acc0 = __builtin_amdgcn_mfma_f32_16x16x32_bf16(a0, bq, acc0, 0, 0, 0);
      acc1 = __builtin_amdgcn_mfma_f32_16x16x32_bf16(a1, bq, acc1, 0, 0, 0);
    }
#pragma unroll
    for (int j = 0; j < 4; ++j) {
      gl[row * 33 + fq * 4 + j] = acc0[j];
      gl[row * 33 + 16 + fq * 4 + j] = acc1[j];
    }
  }
  __syncthreads();
  const int srow = dir ? 63 - t : t;
  unsigned short* hnb = hbf + dir * 32768 + ((t + 1) & 1) * 16384;
  const float* hcur = hf32 + dir * 32768 + (t & 1) * 16384;
  float* hnf = hf32 + dir * 32768 + ((t + 1) & 1) * 16384;
#pragma unroll
  for (int rep = 0; rep < 2; ++rep) {
    int idx = rep * 512 + tid, b = idx >> 5, dl = idx & 31, d = D0 + dl;
    float ar = gl[dl * 33 + b] + bhh[d];
    float az = gl[(32 + dl) * 33 + b] + bhh[512 + d];
    float an = gl[(64 + dl) * 33 + b] + bhh[1024 + d];
    const float* gi = Gi + ((size_t)srow * 32 + b) * 1536;
    float r = sigm_fast(gi[d] + ar);
    float z = sigm_fast(gi[512 + d] + az);
    float n = tanh_fast(gi[1024 + d] + r * an);
    float h2 = (1.f - z) * n + z * hcur[b * 512 + d];
    hnb[b * 512 + d] = f2bf(h2);
    hnf[b * 512 + d] = h2;
    ebo[((size_t)b * 64 + srow) * 1024 + (size_t)dir * 512 + d] = f2bf(h2);
    if (t == 63) hcat[(size_t)b * 1024 + (size_t)dir * 512 + d] = h2;
  }
}

__global__ __launch_bounds__(512) void tanh_s0(const float* __restrict__ s0raw,
                                               float* __restrict__ sf32,
                                               unsigned short* __restrict__ sbf) {
  int idx = blockIdx.x * 512 + threadIdx.x;
  float v = tanhf(s0raw[idx]);
  sf32[idx] = v;
  sbf[idx] = f2bf(v);
}

// Decoder step part 1: gout[b][n] = s_t[b] . Wcat[n] (+decBhh for n>=512).
__global__ __launch_bounds__(512) void dec_proj(
    const unsigned short* __restrict__ Wcat, const float* __restrict__ decBhh,
    const unsigned short* __restrict__ sbf, float* __restrict__ gout, int t) {
  const int g = blockIdx.x, tid = threadIdx.x;
  __shared__ __align__(16) unsigned short slds[32 * 520];
  const unsigned short* sb = sbf + (t & 1) * 16384;
  for (int c = tid; c < 32 * 64; c += 512) {
    int r = c >> 6, seg = c & 63;
    *(short8*)(slds + r * 520 + seg * 8) = *(const short8*)(sb + r * 512 + seg * 8);
  }
  __syncthreads();
  const int w = tid >> 6, lane = tid & 63, fr = lane & 15, fq = lane >> 4;
  const int mt = w >> 2, nt = w & 3;
  int rc = g * 64 + nt * 16 + fr;
  const unsigned short* wrow = Wcat + (size_t)rc * 512;
  f32x4 acc = {0.f, 0.f, 0.f, 0.f};
#pragma unroll
  for (int k0 = 0; k0 < 512; k0 += 32) {
    short8 a = *(const short8*)(slds + (mt * 16 + fr) * 520 + k0 + fq * 8);
    short8 bq = *(const short8*)(wrow + k0 + fq * 8);
    acc = __builtin_amdgcn_mfma_f32_16x16x32_bf16(a, bq, acc, 0, 0, 0);
  }
  float bv = rc < 512 ? 0.f : decBhh[rc - 512];
#pragma unroll
  for (int j = 0; j < 4; ++j)
    gout[(size_t)(mt * 16 + fq * 4 + j) * 2048 + rc] = acc[j] + bv;
}

// Decoder step part 2: scores, softmax, context, gic, gates. One block per batch.
__global__ __launch_bounds__(512) void dec_attn(
    const float* __restrict__ attnV,
    const unsigned short* __restrict__ epf, const unsigned short* __restrict__ ebo,
    const unsigned short* __restrict__ EP2b, const float* __restrict__ Gie,
    const float* __restrict__ gout,
    unsigned short* __restrict__ sbf, float* __restrict__ sf32,
    unsigned short* __restrict__ Zbf, int t) {
  const int b = blockIdx.x, tid = threadIdx.x;
  __shared__ __align__(16) float gout_f[2048];
  __shared__ float raw[64], aaw[64];
  __shared__ float vlds[512];
  vlds[tid] = attnV[tid];
  *(float4*)(gout_f + tid * 4) = *(const float4*)(gout + (size_t)b * 2048 + tid * 4);
  __syncthreads();
  const int s_i = tid >> 3, l8 = tid & 7;
  {
    float part = 0.f;
    const float* gp = gout_f + l8 * 64;
    const unsigned short* ep = epf + ((size_t)b * 64 + s_i) * 512 + l8 * 64;
    const float* vv = vlds + l8 * 64;
#pragma unroll
    for (int jc = 0; jc < 8; ++jc) {
      short8 e8 = *(const short8*)(ep + jc * 8);
      float4 g0 = *(const float4*)(gp + jc * 8);
      float4 g1 = *(const float4*)(gp + jc * 8 + 4);
      float4 v0 = *(const float4*)(vv + jc * 8);
      float4 v1 = *(const float4*)(vv + jc * 8 + 4);
      part += tanh_fast(g0.x + bf2f((unsigned short)e8[0])) * v0.x;
      part += tanh_fast(g0.y + bf2f((unsigned short)e8[1])) * v0.y;
      part += tanh_fast(g0.z + bf2f((unsigned short)e8[2])) * v0.z;
      part += tanh_fast(g0.w + bf2f((unsigned short)e8[3])) * v0.w;
      part += tanh_fast(g1.x + bf2f((unsigned short)e8[4])) * v1.x;
      part += tanh_fast(g1.y + bf2f((unsigned short)e8[5])) * v1.y;
      part += tanh_fast(g1.z + bf2f((unsigned short)e8[6])) * v1.z;
      part += tanh_fast(g1.w + bf2f((unsigned short)e8[7])) * v1.w;
    }
    part += __shfl_xor(part, 1);
    part += __shfl_xor(part, 2);
    part += __shfl_xor(part, 4);
    if (l8 == 0) raw[s_i] = part;
  }
  __syncthreads();
  if (tid < 64) {
    float x = raw[tid];
    float m = x;
#pragma unroll
    for (int k = 1; k < 64; k <<= 1) m = fmaxf(m, __shfl_xor(m, k));
    float e = __expf(x - m);
    float s = e;
#pragma unroll
    for (int k = 1; k < 64; k <<= 1) s += __shfl_xor(s, k);
    aaw[tid] = e * __builtin_amdgcn_rcpf(s);
  }
  __syncthreads();
  float c0 = 0.f, c1 = 0.f, g0a = 0.f, g1a = 0.f, g2a = 0.f;
  {
    const unsigned short* eb = ebo + (size_t)b * 64 * 1024 + tid;
    const unsigned short* e2 = EP2b + (size_t)b * 64 * 1536 + tid;
#pragma unroll 8
    for (int s2 = 0; s2 < 64; ++s2) {
      float a = aaw[s2];
      c0 += a * bf2f(eb[(size_t)s2 * 1024]);
      c1 += a * bf2f(eb[(size_t)s2 * 1024 + 512]);
      g0a += a * bf2f(e2[(size_t)s2 * 1536]);
      g1a += a * bf2f(e2[(size_t)s2 * 1536 + 512]);
      g2a += a * bf2f(e2[(size_t)s2 * 1536 + 1024]);
    }
  }
  const float* gie = Gie + ((size_t)t * 32 + b) * 1536;
  float sprev = sf32[(t & 1) * 16384 + b * 512 + tid];
  float rr = sigm_fast(gie[tid] + g0a + gout_f[512 + tid]);
  float zz = sigm_fast(gie[512 + tid] + g1a + gout_f[1024 + tid]);
  float nn = tanh_fast(gie[1024 + tid] + g2a + rr * gout_f[1536 + tid]);
  float s2v = (1.f - zz) * nn + zz * sprev;
  sbf[((t + 1) & 1) * 16384 + b * 512 + tid] = f2bf(s2v);
  sf32[((t + 1) & 1) * 16384 + b * 512 + tid] = s2v;
  size_t zrow = ((size_t)t * 32 + b) * 2048;
  Zbf[zrow + tid] = f2bf(s2v);
  Zbf[zrow + 512 + tid] = f2bf(c0);
  Zbf[zrow + 1024 + tid] = f2bf(c1);
}

extern "C" void kernel_launch(void* const* d_in, const int* in_sizes, int n_in,
                              void* d_out, int out_size, void* d_ws, size_t ws_size,
                              hipStream_t stream) {
  (void)in_sizes; (void)n_in; (void)out_size;
  const int* src = (const int*)d_in[0];
  const int* trg = (const int*)d_in[1];
  const float* emb = (const float*)d_in[2];
  const float* encf_Wih = (const float*)d_in[3];
  const float* encf_Whh = (const float*)d_in[4];
  const float* encf_bih = (const float*)d_in[5];
  const float* encf_bhh = (const float*)d_in[6];
  const float* encb_Wih = (const float*)d_in[7];
  const float* encb_Whh = (const float*)d_in[8];
  const float* encb_bih = (const float*)d_in[9];
  const float* encb_bhh = (const float*)d_in[10];
  const float* fc_W = (const float*)d_in[11];
  const float* fc_b = (const float*)d_in[12];
  const float* attn_W = (const float*)d_in[13];
  const float* attn_v = (const float*)d_in[14];
  const float* dec_Wih = (const float*)d_in[15];
  const float* dec_Whh = (const float*)d_in[16];
  const float* dec_bih = (const float*)d_in[17];
  const float* dec_bhh = (const float*)d_in[18];
  const float* out_W = (const float*)d_in[19];
  const float* out_b = (const float*)d_in[20];
  float* out = (float*)d_out;

  char* p = (char*)d_ws;
  size_t off = 0;
  auto alloc = [&](size_t bytes) {
    void* r = p + off;
    off = (off + bytes + 255) & ~(size_t)255;
    return r;
  };
  unsigned short* xbf = (unsigned short*)alloc((size_t)2048 * 512 * 2);
  unsigned short* ebf = (unsigned short*)alloc((size_t)1536 * 512 * 2);
  unsigned short* Zbf = (unsigned short*)alloc((size_t)1536 * 2048 * 2);
  float* Gif = (float*)alloc((size_t)2048 * 1536 * 4);
  float* Gib = (float*)alloc((size_t)2048 * 1536 * 4);
  float* Gie = (float*)alloc((size_t)1536 * 1536 * 4);
  unsigned short* ebo = (unsigned short*)alloc((size_t)2048 * 1024 * 2);
  unsigned short* epf = (unsigned short*)alloc((size_t)2048 * 512 * 2);
  unsigned short* EP2b = (unsigned short*)alloc((size_t)2048 * 1536 * 2);
  unsigned short* whFbf = (unsigned short*)alloc((size_t)1536 * 512 * 2);
  unsigned short* whBbf = (unsigned short*)alloc((size_t)1536 * 512 * 2);
  unsigned short* Wcat = (unsigned short*)alloc((size_t)2048 * 512 * 2);
  unsigned short* hbf = (unsigned short*)alloc((size_t)2 * 2 * 32 * 512 * 2);
  float* hf32 = (float*)alloc((size_t)2 * 2 * 32 * 512 * 4);
  float* hcat = (float*)alloc((size_t)32 * 1024 * 4);
  float* s0raw = (float*)alloc((size_t)32 * 512 * 4);
  unsigned short* sbf = (unsigned short*)alloc((size_t)2 * 32 * 512 * 2);
  float* sf32 = (float*)alloc((size_t)2 * 32 * 512 * 4);
  float* gout = (float*)alloc((size_t)32 * 2048 * 4);
  unsigned short* outWbf = (unsigned short*)alloc((size_t)32000 * 2048 * 2);
  const bool bigB = (off <= ws_size);

  hipMemsetAsync(hbf, 0, (size_t)2 * 2 * 32 * 512 * 2, stream);
  hipMemsetAsync(hf32, 0, (size_t)2 * 2 * 32 * 512 * 4, stream);
  hipMemsetAsync(d_out, 0, (size_t)32 * 32000 * 4, stream);

  prep_gather<<<3584, 128, 0, stream>>>(src, trg, emb, xbf, ebf, Zbf);
  cvt_rows<<<1536, 64, 0, stream>>>(encf_Whh, 512, whFbf);
  cvt_rows<<<1536, 64, 0, stream>>>(encb_Whh, 512, whBbf);
  cvt_rows<<<512, 64, 0, stream>>>(attn_W, 1536, Wcat);              // sproj part
  cvt_rows<<<1536, 64, 0, stream>>>(dec_Whh, 512, Wcat + (size_t)512 * 512);

  gemm_kernel<true, false, false><<<dim3(16, 12), 256, 0, stream>>>(
      xbf, 512, encf_Wih, 512, 0, encf_bih, Gif, 1536, 512, 2048, 0);
  gemm_kernel<true, false, false><<<dim3(16, 12), 256, 0, stream>>>(
      xbf, 512, encb_Wih, 512, 0, encb_bih, Gib, 1536, 512, 2048, 0);
  gemm_kernel<true, false, false><<<dim3(12, 12), 256, 0, stream>>>(
      ebf, 512, dec_Wih, 1536, 0, dec_bih, Gie, 1536, 512, 1536, 0);

  // encoder steps; piggyback out_W bf16 conversion on idle CUs (200 blocks/step)
  const int nCvt = bigB ? 200 : 0;
  for (int t = 0; t < 64; ++t)
    enc_step<<<32 + nCvt, 512, 0, stream>>>(Gif, Gib, whFbf, whBbf, encf_bhh, encb_bhh,
                                            hbf, hf32, ebo, hcat, out_W, outWbf, nCvt, t);

  gemm_kernel<false, false, false><<<dim3(1, 4), 256, 0, stream>>>(
      hcat, 1024, fc_W, 1024, 0, fc_b, s0raw, 512, 1024, 32, 0);
  tanh_s0<<<32, 512, 0, stream>>>(s0raw, sf32, sbf);

  gemm_kernel<true, false, true><<<dim3(16, 4), 256, 0, stream>>>(
      ebo, 1024, attn_W, 1536, 512, nullptr, epf, 512, 1024, 2048, 0);
  gemm_kernel<true, false, true><<<dim3(16, 12), 256, 0, stream>>>(
      ebo, 1024, dec_Wih, 1536, 512, nullptr, EP2b, 1536, 1024, 2048, 0);

  for (int t = 0; t < 47; ++t) {
    dec_proj<<<32, 512, 0, stream>>>(Wcat, dec_bhh, sbf, gout, t);
    dec_attn<<<32, 512, 0, stream>>>(attn_v, epf, ebo, EP2b, Gie, gout,
                                     sbf, sf32, Zbf, t);
  }

  if (bigB)
    gemm_big<<<3000, 256, 0, stream>>>(Zbf, 2048, outWbf, 2048, out_b,
                                       out, 32000, 2048, 1504, 32);
  else
    gemm_kernel<true, false, false><<<dim3(12, 250), 256, 0, stream>>>(
        Zbf, 2048, out_W, 2048, 0, out_b, out, 32000, 2048, 1504, 32);
}

// Round 9
// 1887.614 us; speedup vs baseline: 1.7463x; 1.0498x over previous
//
#include <hip/hip_runtime.h>
#include <stdint.h>
#include <stddef.h>

typedef __attribute__((ext_vector_type(8))) short short8;
typedef __attribute__((ext_vector_type(4))) float f32x4;
typedef unsigned int u32;

__device__ inline unsigned short f2bf(float f) {
  union { float f; uint32_t u; } v; v.f = f;
  uint32_t u = v.u;
  u += 0x7FFFu + ((u >> 16) & 1u);
  return (unsigned short)(u >> 16);
}
__device__ inline float bf2f(unsigned short h) {
  union { uint32_t u; float f; } v; v.u = ((uint32_t)h) << 16; return v.f;
}
__device__ inline short8 pack8(float4 a, float4 b) {
  short8 r;
  r[0] = (short)f2bf(a.x); r[1] = (short)f2bf(a.y);
  r[2] = (short)f2bf(a.z); r[3] = (short)f2bf(a.w);
  r[4] = (short)f2bf(b.x); r[5] = (short)f2bf(b.y);
  r[6] = (short)f2bf(b.z); r[7] = (short)f2bf(b.w);
  return r;
}
__device__ inline float tanh_fast(float x) {
  float xc = fminf(fmaxf(x, -9.f), 9.f);
  float e = __expf(2.f * xc);
  return (e - 1.f) * __builtin_amdgcn_rcpf(e + 1.f);
}
__device__ inline float sigm_fast(float x) {
  float xc = fminf(fmaxf(x, -30.f), 30.f);
  return __builtin_amdgcn_rcpf(1.f + __expf(-xc));
}
// async global->LDS, 16 bytes per lane (wave-uniform LDS base + lane*16)
__device__ inline void gl_lds16(const unsigned short* g, unsigned short* l) {
  __builtin_amdgcn_global_load_lds(
      (const __attribute__((address_space(1))) u32*)g,
      (__attribute__((address_space(3))) u32*)l, 16, 0, 0);
}

// Gather + bf16-convert embeddings.
__global__ __launch_bounds__(128) void prep_gather(
    const int* __restrict__ src, const int* __restrict__ trg,
    const float* __restrict__ emb,
    unsigned short* __restrict__ xbf, unsigned short* __restrict__ ebf,
    unsigned short* __restrict__ Zbf) {
  int r = blockIdx.x, tid = threadIdx.x;
  if (r < 2048) {
    int b = r & 31, s = r >> 5;
    int tok = src[b * 64 + s];
    const float* e = emb + (size_t)tok * 512;
    float4 v = *(const float4*)(e + tid * 4);
    unsigned short* dst = xbf + (size_t)r * 512 + tid * 4;
    dst[0] = f2bf(v.x); dst[1] = f2bf(v.y); dst[2] = f2bf(v.z); dst[3] = f2bf(v.w);
  } else {
    int rr = r - 2048;
    int t = rr >> 5, b = rr & 31;
    unsigned short* dst = ebf + (size_t)rr * 512 + tid * 4;
    if (t < 47) {
      int tok = trg[t * 32 + b];
      const float* e = emb + (size_t)tok * 512;
      float4 v = *(const float4*)(e + tid * 4);
      unsigned short q0 = f2bf(v.x), q1 = f2bf(v.y), q2 = f2bf(v.z), q3 = f2bf(v.w);
      dst[0] = q0; dst[1] = q1; dst[2] = q2; dst[3] = q3;
      unsigned short* zd = Zbf + (size_t)rr * 2048 + 1536 + tid * 4;
      zd[0] = q0; zd[1] = q1; zd[2] = q2; zd[3] = q3;
    } else {
      dst[0] = 0; dst[1] = 0; dst[2] = 0; dst[3] = 0;
    }
  }
}

// Convert rows of a f32 matrix (leading dim srcld, 512 cols used) to bf16 [R][512].
__global__ __launch_bounds__(64) void cvt_rows(const float* __restrict__ src, int srcld,
                                               unsigned short* __restrict__ dst) {
  int r = blockIdx.x, c = threadIdx.x * 8;
  const float* s = src + (size_t)r * srcld + c;
  *(short8*)(dst + (size_t)r * 512 + c) = pack8(*(const float4*)s, *(const float4*)(s + 4));
}

// C[m,n] = sum_k A[m,k]*B[n,k] (+bias[n]). 128x128 tile, BK=32, 4 waves.
template <bool ABF, bool BBF, bool WBF>
__global__ __launch_bounds__(256) void gemm_kernel(
    const void* __restrict__ Av, int lda,
    const void* __restrict__ Bv, int ldb, int bco,
    const float* __restrict__ bias,
    void* __restrict__ Cv, int ldc,
    int K, int Mvalid, int row_off) {
  __shared__ __align__(16) unsigned short As[128 * 32];
  __shared__ __align__(16) unsigned short Bs[128 * 32];
  const int tid = threadIdx.x;
  const int m0 = blockIdx.x * 128, n0 = blockIdx.y * 128;
  const int w = tid >> 6, lane = tid & 63;
  const int wm = w >> 1, wn = w & 1;
  const int fr = lane & 15, fq = lane >> 4;
  f32x4 acc[4][4];
#pragma unroll
  for (int mi = 0; mi < 4; ++mi)
#pragma unroll
    for (int ni = 0; ni < 4; ++ni) acc[mi][ni] = (f32x4){0.f, 0.f, 0.f, 0.f};
  for (int k0 = 0; k0 < K; k0 += 32) {
#pragma unroll
    for (int p = 0; p < 2; ++p) {
      int idx = p * 256 + tid;
      int row = idx >> 2, seg = idx & 3;
      if (ABF) {
        const unsigned short* Ab = (const unsigned short*)Av;
        *(short8*)(As + row * 32 + seg * 8) =
            *(const short8*)(Ab + (size_t)(m0 + row) * lda + k0 + seg * 8);
      } else {
        const float* Af = (const float*)Av;
        const float* ap = Af + (size_t)(m0 + row) * lda + k0 + seg * 8;
        *(short8*)(As + row * 32 + seg * 8) = pack8(*(const float4*)ap, *(const float4*)(ap + 4));
      }
      if (BBF) {
        const unsigned short* Bb = (const unsigned short*)Bv;
        *(short8*)(Bs + row * 32 + seg * 8) =
            *(const short8*)(Bb + (size_t)(n0 + row) * ldb + bco + k0 + seg * 8);
      } else {
        const float* Bf = (const float*)Bv;
        const float* bp = Bf + (size_t)(n0 + row) * ldb + bco + k0 + seg * 8;
        *(short8*)(Bs + row * 32 + seg * 8) = pack8(*(const float4*)bp, *(const float4*)(bp + 4));
      }
    }
    __syncthreads();
    short8 af[4], bfr[4];
#pragma unroll
    for (int mi = 0; mi < 4; ++mi)
      af[mi] = *(const short8*)(As + (wm * 64 + mi * 16 + fr) * 32 + fq * 8);
#pragma unroll
    for (int ni = 0; ni < 4; ++ni)
      bfr[ni] = *(const short8*)(Bs + (wn * 64 + ni * 16 + fr) * 32 + fq * 8);
#pragma unroll
    for (int mi = 0; mi < 4; ++mi)
#pragma unroll
      for (int ni = 0; ni < 4; ++ni)
        acc[mi][ni] = __builtin_amdgcn_mfma_f32_16x16x32_bf16(af[mi], bfr[ni], acc[mi][ni], 0, 0, 0);
    __syncthreads();
  }
#pragma unroll
  for (int mi = 0; mi < 4; ++mi)
#pragma unroll
    for (int ni = 0; ni < 4; ++ni) {
      int col = n0 + wn * 64 + ni * 16 + fr;
      float bv = bias ? bias[col] : 0.f;
#pragma unroll
      for (int j = 0; j < 4; ++j) {
        int rowm = m0 + wm * 64 + mi * 16 + fq * 4 + j;
        if (rowm < Mvalid) {
          float val = acc[mi][ni][j] + bv;
          if (WBF)
            ((unsigned short*)Cv)[(size_t)(rowm + row_off) * ldc + col] = f2bf(val);
          else
            ((float*)Cv)[(size_t)(rowm + row_off) * ldc + col] = val;
        }
      }
    }
}

// Output projection, 8-phase 256x256 schedule (T2 swizzle + T3/T4 counted
// vmcnt + T5 setprio). A=Zbf[1536][2048], B=outWbf[32000][2048], C f32.
// LDS 128KiB dynamic: [A|B] x [2 dbuf] x [2 half: 128 rows x 64 cols bf16].
// st_16x32 swizzle: phys_byte = byte ^ ((byte>>9 & 1) << 5), applied as
// inverse-permuted global source (gl_lds writes linearly) + swizzled ds_read.
__global__ __launch_bounds__(512, 1) void gemm_big8(
    const unsigned short* __restrict__ A,
    const unsigned short* __restrict__ B,
    const float* __restrict__ bias,
    float* __restrict__ C) {
  extern __shared__ char lds[];
  char* LA = lds;
  char* LB = lds + 65536;
  const int tid = threadIdx.x;
  const int w = tid >> 6, lane = tid & 63;
  // bijective XCD swizzle: 750 wgs = 8 XCDs, q=93, r=6
  int wg = blockIdx.x;
  {
    int x = wg & 7, i = wg >> 3;
    wg = (x < 6 ? x * 94 : 564 + (x - 6) * 93) + i;
  }
  const int m0 = (wg % 6) * 256, n0 = (wg / 6) * 256;
  const int wm = w >> 2, wn = w & 3;
  const int fr = lane & 15, fq = lane >> 4;

  // stage one half-tile (128 rows x 64 cols) of tile kt into buf c
  auto stage = [&](const unsigned short* G, char* L, int rowbase, int kt, int h, int c) {
#pragma unroll
    for (int j = 0; j < 2; ++j) {
      int pbh = j * 8192 + w * 1024;           // wave-uniform LDS offset
      int pl = pbh + lane * 16;                // this lane's physical byte
      int lb = pl ^ (((pl >> 9) & 1) << 5);    // logical byte (involution)
      int rl = lb >> 7, ch = (lb >> 4) & 7;
      gl_lds16(G + (size_t)(rowbase + h * 128 + rl) * 2048 + kt * 64 + ch * 8,
               (unsigned short*)(L + c * 32768 + h * 16384 + pbh));
    }
  };

  f32x4 acc[8][4];
#pragma unroll
  for (int mi = 0; mi < 8; ++mi)
#pragma unroll
    for (int ni = 0; ni < 4; ++ni) acc[mi][ni] = (f32x4){0.f, 0.f, 0.f, 0.f};

  // prologue: tile 0 into buf 0
  stage(A, LA, m0, 0, 0, 0); stage(B, LB, n0, 0, 0, 0);
  stage(A, LA, m0, 0, 1, 0); stage(B, LB, n0, 0, 1, 0);
  asm volatile("s_waitcnt vmcnt(0)" ::: "memory");
  __builtin_amdgcn_s_barrier();

  short8 bfrag[8];
  for (int kt = 0; kt < 32; ++kt) {
    const int c = kt & 1;
    char* Abuf = LA + c * 32768;
    char* Bbuf = LB + c * 32768;
#pragma unroll
    for (int p = 0; p < 4; ++p) {
      if (kt < 31) {
        if (p == 0) {
          stage(A, LA, m0, kt + 1, 0, c ^ 1);
          stage(B, LB, n0, kt + 1, 0, c ^ 1);
        } else if (p == 1) {
          stage(A, LA, m0, kt + 1, 1, c ^ 1);
          stage(B, LB, n0, kt + 1, 1, c ^ 1);
        }
      }
      if (p == 0) {
#pragma unroll
        for (int ni = 0; ni < 4; ++ni)
#pragma unroll
          for (int ks = 0; ks < 2; ++ks) {
            int n = wn * 64 + ni * 16 + fr;
            int h = n >> 7, nl = n & 127;
            int lb = nl * 128 + ks * 64 + fq * 16;
            int pb = lb ^ (((lb >> 9) & 1) << 5);
            bfrag[ni * 2 + ks] = *(const short8*)(Bbuf + h * 16384 + pb);
          }
      }
      short8 afrag[4];
#pragma unroll
      for (int q = 0; q < 2; ++q)
#pragma unroll
        for (int ks = 0; ks < 2; ++ks) {
          int r = wm * 128 + (2 * p + q) * 16 + fr;
          int h = r >> 7, rl = r & 127;
          int lb = rl * 128 + ks * 64 + fq * 16;
          int pb = lb ^ (((lb >> 9) & 1) << 5);
          afrag[q * 2 + ks] = *(const short8*)(Abuf + h * 16384 + pb);
        }
      __builtin_amdgcn_s_setprio(1);
#pragma unroll
      for (int q = 0; q < 2; ++q)
#pragma unroll
        for (int ni = 0; ni < 4; ++ni)
#pragma unroll
          for (int ks = 0; ks < 2; ++ks)
            acc[2 * p + q][ni] = __builtin_amdgcn_mfma_f32_16x16x32_bf16(
                afrag[q * 2 + ks], bfrag[ni * 2 + ks], acc[2 * p + q][ni], 0, 0, 0);
      __builtin_amdgcn_s_setprio(0);
      if (p == 3) asm volatile("s_waitcnt vmcnt(0)" ::: "memory");
      __builtin_amdgcn_s_barrier();
    }
  }
#pragma unroll
  for (int mi = 0; mi < 8; ++mi)
#pragma unroll
    for (int ni = 0; ni < 4; ++ni) {
      int col = n0 + wn * 64 + ni * 16 + fr;
      float bv = bias[col];
#pragma unroll
      for (int j = 0; j < 4; ++j) {
        int row = m0 + wm * 128 + mi * 16 + fq * 4 + j;
        if (row < 1504) C[(size_t)(row + 32) * 32000 + col] = acc[mi][ni][j] + bv;
      }
    }
}

// One encoder GRU step, both directions. Blocks 0..31: dir=blk>>4, 32-d slice.
// Blocks 32..231: piggyback out_W f32->bf16 conversion (idle-CU work).
__global__ __launch_bounds__(512) void enc_step(
    const float* __restrict__ Gif, const float* __restrict__ Gib,
    const unsigned short* __restrict__ whFbf, const unsigned short* __restrict__ whBbf,
    const float* __restrict__ bhhF, const float* __restrict__ bhhB,
    unsigned short* __restrict__ hbf,   // [dir][2][32][512] bf16
    float* __restrict__ hf32,           // [dir][2][32][512] f32
    unsigned short* __restrict__ ebo,   // [b][s][1024] bf16
    float* __restrict__ hcat,           // [b][1024] f32
    const float* __restrict__ outW, unsigned short* __restrict__ outWbf, int nCvt,
    int t) {
  const int blk = blockIdx.x, tid = threadIdx.x;
  if (blk >= 32) {
    if (blk - 32 < nCvt) {
      size_t base4 = ((size_t)t * nCvt + (blk - 32)) * 1280;
      for (int i = tid; i < 1280; i += 512) {
        float4 v = ((const float4*)outW)[base4 + i];
        unsigned short* d = outWbf + (base4 + i) * 4;
        d[0] = f2bf(v.x); d[1] = f2bf(v.y); d[2] = f2bf(v.z); d[3] = f2bf(v.w);
      }
    }
    return;
  }
  const int dir = blk >> 4, slice = blk & 15, D0 = slice * 32;
  const unsigned short* Wbf = dir ? whBbf : whFbf;
  const float* Gi = dir ? Gib : Gif;
  const float* bhh = dir ? bhhB : bhhF;
  __shared__ __align__(16) unsigned short hlds[32 * 520];
  __shared__ __align__(16) float gl[96 * 33];
  const unsigned short* hb = hbf + dir * 32768 + (t & 1) * 16384;
  for (int c = tid; c < 32 * 64; c += 512) {
    int r = c >> 6, seg = c & 63;
    *(short8*)(hlds + r * 520 + seg * 8) = *(const short8*)(hb + r * 512 + seg * 8);
  }
  __syncthreads();
  const int w = tid >> 6, lane = tid & 63, fr = lane & 15, fq = lane >> 4;
  if (w < 6) {
    int row = w * 16 + fr;
    int gr = (row >> 5) * 512 + D0 + (row & 31);
    const unsigned short* wrow = Wbf + (size_t)gr * 512;
    f32x4 acc0 = {0.f, 0.f, 0.f, 0.f}, acc1 = {0.f, 0.f, 0.f, 0.f};
#pragma unroll
    for (int k0 = 0; k0 < 512; k0 += 32) {
      short8 bq = *(const short8*)(wrow + k0 + fq * 8);
      short8 a0 = *(const short8*)(hlds + fr * 520 + k0 + fq * 8);
      short8 a1 = *(const short8*)(hlds + (16 + fr) * 520 + k0 + fq * 8);
      acc0 = __builtin_amdgcn_mfma_f32_16x16x32_bf16(a0, bq, acc0, 0, 0, 0);
      acc1 = __builtin_amdgcn_mfma_f32_16x16x32_bf16(a1, bq, acc1, 0, 0, 0);
    }
#pragma unroll
    for (int j = 0; j < 4; ++j) {
      gl[row * 33 + fq * 4 + j] = acc0[j];
      gl[row * 33 + 16 + fq * 4 + j] = acc1[j];
    }
  }
  __syncthreads();
  const int srow = dir ? 63 - t : t;
  unsigned short* hnb = hbf + dir * 32768 + ((t + 1) & 1) * 16384;
  const float* hcur = hf32 + dir * 32768 + (t & 1) * 16384;
  float* hnf = hf32 + dir * 32768 + ((t + 1) & 1) * 16384;
#pragma unroll
  for (int rep = 0; rep < 2; ++rep) {
    int idx = rep * 512 + tid, b = idx >> 5, dl = idx & 31, d = D0 + dl;
    float ar = gl[dl * 33 + b] + bhh[d];
    float az = gl[(32 + dl) * 33 + b] + bhh[512 + d];
    float an = gl[(64 + dl) * 33 + b] + bhh[1024 + d];
    const float* gi = Gi + ((size_t)srow * 32 + b) * 1536;
    float r = sigm_fast(gi[d] + ar);
    float z = sigm_fast(gi[512 + d] + az);
    float n = tanh_fast(gi[1024 + d] + r * an);
    float h2 = (1.f - z) * n + z * hcur[b * 512 + d];
    hnb[b * 512 + d] = f2bf(h2);
    hnf[b * 512 + d] = h2;
    ebo[((size_t)b * 64 + srow) * 1024 + (size_t)dir * 512 + d] = f2bf(h2);
    if (t == 63) hcat[(size_t)b * 1024 + (size_t)dir * 512 + d] = h2;
  }
}

__global__ __launch_bounds__(512) void tanh_s0(const float* __restrict__ s0raw,
                                               float* __restrict__ sf32,
                                               unsigned short* __restrict__ sbf) {
  int idx = blockIdx.x * 512 + threadIdx.x;
  float v = tanhf(s0raw[idx]);
  sf32[idx] = v;
  sbf[idx] = f2bf(v);
}

// Decoder step part 1: gout[b][n] = s_t[b] . Wcat[n] (+decBhh for n>=512).
__global__ __launch_bounds__(512) void dec_proj(
    const unsigned short* __restrict__ Wcat, const float* __restrict__ decBhh,
    const unsigned short* __restrict__ sbf, float* __restrict__ gout, int t) {
  const int g = blockIdx.x, tid = threadIdx.x;
  __shared__ __align__(16) unsigned short slds[32 * 520];
  const unsigned short* sb = sbf + (t & 1) * 16384;
  for (int c = tid; c < 32 * 64; c += 512) {
    int r = c >> 6, seg = c & 63;
    *(short8*)(slds + r * 520 + seg * 8) = *(const short8*)(sb + r * 512 + seg * 8);
  }
  __syncthreads();
  const int w = tid >> 6, lane = tid & 63, fr = lane & 15, fq = lane >> 4;
  const int mt = w >> 2, nt = w & 3;
  int rc = g * 64 + nt * 16 + fr;
  const unsigned short* wrow = Wcat + (size_t)rc * 512;
  f32x4 acc = {0.f, 0.f, 0.f, 0.f};
#pragma unroll
  for (int k0 = 0; k0 < 512; k0 += 32) {
    short8 a = *(const short8*)(slds + (mt * 16 + fr) * 520 + k0 + fq * 8);
    short8 bq = *(const short8*)(wrow + k0 + fq * 8);
    acc = __builtin_amdgcn_mfma_f32_16x16x32_bf16(a, bq, acc, 0, 0, 0);
  }
  float bv = rc < 512 ? 0.f : decBhh[rc - 512];
#pragma unroll
  for (int j = 0; j < 4; ++j)
    gout[(size_t)(mt * 16 + fq * 4 + j) * 2048 + rc] = acc[j] + bv;
}

// Decoder step part 2: scores, softmax, context, gic, gates. One block per batch.
__global__ __launch_bounds__(512) void dec_attn(
    const float* __restrict__ attnV,
    const unsigned short* __restrict__ epf, const unsigned short* __restrict__ ebo,
    const unsigned short* __restrict__ EP2b, const float* __restrict__ Gie,
    const float* __restrict__ gout,
    unsigned short* __restrict__ sbf, float* __restrict__ sf32,
    unsigned short* __restrict__ Zbf, int t) {
  const int b = blockIdx.x, tid = threadIdx.x;
  __shared__ __align__(16) float gout_f[2048];
  __shared__ float raw[64], aaw[64];
  __shared__ float vlds[512];
  vlds[tid] = attnV[tid];
  *(float4*)(gout_f + tid * 4) = *(const float4*)(gout + (size_t)b * 2048 + tid * 4);
  __syncthreads();
  const int s_i = tid >> 3, l8 = tid & 7;
  {
    float part = 0.f;
    const float* gp = gout_f + l8 * 64;
    const unsigned short* ep = epf + ((size_t)b * 64 + s_i) * 512 + l8 * 64;
    const float* vv = vlds + l8 * 64;
#pragma unroll
    for (int jc = 0; jc < 8; ++jc) {
      short8 e8 = *(const short8*)(ep + jc * 8);
      float4 g0 = *(const float4*)(gp + jc * 8);
      float4 g1 = *(const float4*)(gp + jc * 8 + 4);
      float4 v0 = *(const float4*)(vv + jc * 8);
      float4 v1 = *(const float4*)(vv + jc * 8 + 4);
      part += tanh_fast(g0.x + bf2f((unsigned short)e8[0])) * v0.x;
      part += tanh_fast(g0.y + bf2f((unsigned short)e8[1])) * v0.y;
      part += tanh_fast(g0.z + bf2f((unsigned short)e8[2])) * v0.z;
      part += tanh_fast(g0.w + bf2f((unsigned short)e8[3])) * v0.w;
      part += tanh_fast(g1.x + bf2f((unsigned short)e8[4])) * v1.x;
      part += tanh_fast(g1.y + bf2f((unsigned short)e8[5])) * v1.y;
      part += tanh_fast(g1.z + bf2f((unsigned short)e8[6])) * v1.z;
      part += tanh_fast(g1.w + bf2f((unsigned short)e8[7])) * v1.w;
    }
    part += __shfl_xor(part, 1);
    part += __shfl_xor(part, 2);
    part += __shfl_xor(part, 4);
    if (l8 == 0) raw[s_i] = part;
  }
  __syncthreads();
  if (tid < 64) {
    float x = raw[tid];
    float m = x;
#pragma unroll
    for (int k = 1; k < 64; k <<= 1) m = fmaxf(m, __shfl_xor(m, k));
    float e = __expf(x - m);
    float s = e;
#pragma unroll
    for (int k = 1; k < 64; k <<= 1) s += __shfl_xor(s, k);
    aaw[tid] = e * __builtin_amdgcn_rcpf(s);
  }
  __syncthreads();
  float c0 = 0.f, c1 = 0.f, g0a = 0.f, g1a = 0.f, g2a = 0.f;
  {
    const unsigned short* eb = ebo + (size_t)b * 64 * 1024 + tid;
    const unsigned short* e2 = EP2b + (size_t)b * 64 * 1536 + tid;
#pragma unroll 8
    for (int s2 = 0; s2 < 64; ++s2) {
      float a = aaw[s2];
      c0 += a * bf2f(eb[(size_t)s2 * 1024]);
      c1 += a * bf2f(eb[(size_t)s2 * 1024 + 512]);
      g0a += a * bf2f(e2[(size_t)s2 * 1536]);
      g1a += a * bf2f(e2[(size_t)s2 * 1536 + 512]);
      g2a += a * bf2f(e2[(size_t)s2 * 1536 + 1024]);
    }
  }
  const float* gie = Gie + ((size_t)t * 32 + b) * 1536;
  float sprev = sf32[(t & 1) * 16384 + b * 512 + tid];
  float rr = sigm_fast(gie[tid] + g0a + gout_f[512 + tid]);
  float zz = sigm_fast(gie[512 + tid] + g1a + gout_f[1024 + tid]);
  float nn = tanh_fast(gie[1024 + tid] + g2a + rr * gout_f[1536 + tid]);
  float s2v = (1.f - zz) * nn + zz * sprev;
  sbf[((t + 1) & 1) * 16384 + b * 512 + tid] = f2bf(s2v);
  sf32[((t + 1) & 1) * 16384 + b * 512 + tid] = s2v;
  size_t zrow = ((size_t)t * 32 + b) * 2048;
  Zbf[zrow + tid] = f2bf(s2v);
  Zbf[zrow + 512 + tid] = f2bf(c0);
  Zbf[zrow + 1024 + tid] = f2bf(c1);
}

extern "C" void kernel_launch(void* const* d_in, const int* in_sizes, int n_in,
                              void* d_out, int out_size, void* d_ws, size_t ws_size,
                              hipStream_t stream) {
  (void)in_sizes; (void)n_in; (void)out_size;
  const int* src = (const int*)d_in[0];
  const int* trg = (const int*)d_in[1];
  const float* emb = (const float*)d_in[2];
  const float* encf_Wih = (const float*)d_in[3];
  const float* encf_Whh = (const float*)d_in[4];
  const float* encf_bih = (const float*)d_in[5];
  const float* encf_bhh = (const float*)d_in[6];
  const float* encb_Wih = (const float*)d_in[7];
  const float* encb_Whh = (const float*)d_in[8];
  const float* encb_bih = (const float*)d_in[9];
  const float* encb_bhh = (const float*)d_in[10];
  const float* fc_W = (const float*)d_in[11];
  const float* fc_b = (const float*)d_in[12];
  const float* attn_W = (const float*)d_in[13];
  const float* attn_v = (const float*)d_in[14];
  const float* dec_Wih = (const float*)d_in[15];
  const float* dec_Whh = (const float*)d_in[16];
  const float* dec_bih = (const float*)d_in[17];
  const float* dec_bhh = (const float*)d_in[18];
  const float* out_W = (const float*)d_in[19];
  const float* out_b = (const float*)d_in[20];
  float* out = (float*)d_out;

  char* p = (char*)d_ws;
  size_t off = 0;
  auto alloc = [&](size_t bytes) {
    void* r = p + off;
    off = (off + bytes + 255) & ~(size_t)255;
    return r;
  };
  unsigned short* xbf = (unsigned short*)alloc((size_t)2048 * 512 * 2);
  unsigned short* ebf = (unsigned short*)alloc((size_t)1536 * 512 * 2);
  unsigned short* Zbf = (unsigned short*)alloc((size_t)1536 * 2048 * 2);
  float* Gif = (float*)alloc((size_t)2048 * 1536 * 4);
  float* Gib = (float*)alloc((size_t)2048 * 1536 * 4);
  float* Gie = (float*)alloc((size_t)1536 * 1536 * 4);
  unsigned short* ebo = (unsigned short*)alloc((size_t)2048 * 1024 * 2);
  unsigned short* epf = (unsigned short*)alloc((size_t)2048 * 512 * 2);
  unsigned short* EP2b = (unsigned short*)alloc((size_t)2048 * 1536 * 2);
  unsigned short* whFbf = (unsigned short*)alloc((size_t)1536 * 512 * 2);
  unsigned short* whBbf = (unsigned short*)alloc((size_t)1536 * 512 * 2);
  unsigned short* Wcat = (unsigned short*)alloc((size_t)2048 * 512 * 2);
  unsigned short* hbf = (unsigned short*)alloc((size_t)2 * 2 * 32 * 512 * 2);
  float* hf32 = (float*)alloc((size_t)2 * 2 * 32 * 512 * 4);
  float* hcat = (float*)alloc((size_t)32 * 1024 * 4);
  float* s0raw = (float*)alloc((size_t)32 * 512 * 4);
  unsigned short* sbf = (unsigned short*)alloc((size_t)2 * 32 * 512 * 2);
  float* sf32 = (float*)alloc((size_t)2 * 32 * 512 * 4);
  float* gout = (float*)alloc((size_t)32 * 2048 * 4);
  unsigned short* outWbf = (unsigned short*)alloc((size_t)32000 * 2048 * 2);
  const bool bigB = (off <= ws_size);

  hipMemsetAsync(hbf, 0, (size_t)2 * 2 * 32 * 512 * 2, stream);
  hipMemsetAsync(hf32, 0, (size_t)2 * 2 * 32 * 512 * 4, stream);
  hipMemsetAsync(d_out, 0, (size_t)32 * 32000 * 4, stream);

  prep_gather<<<3584, 128, 0, stream>>>(src, trg, emb, xbf, ebf, Zbf);
  cvt_rows<<<1536, 64, 0, stream>>>(encf_Whh, 512, whFbf);
  cvt_rows<<<1536, 64, 0, stream>>>(encb_Whh, 512, whBbf);
  cvt_rows<<<512, 64, 0, stream>>>(attn_W, 1536, Wcat);              // sproj part
  cvt_rows<<<1536, 64, 0, stream>>>(dec_Whh, 512, Wcat + (size_t)512 * 512);

  gemm_kernel<true, false, false><<<dim3(16, 12), 256, 0, stream>>>(
      xbf, 512, encf_Wih, 512, 0, encf_bih, Gif, 1536, 512, 2048, 0);
  gemm_kernel<true, false, false><<<dim3(16, 12), 256, 0, stream>>>(
      xbf, 512, encb_Wih, 512, 0, encb_bih, Gib, 1536, 512, 2048, 0);
  gemm_kernel<true, false, false><<<dim3(12, 12), 256, 0, stream>>>(
      ebf, 512, dec_Wih, 1536, 0, dec_bih, Gie, 1536, 512, 1536, 0);

  // encoder steps; piggyback out_W bf16 conversion on idle CUs (200 blocks/step)
  const int nCvt = bigB ? 200 : 0;
  for (int t = 0; t < 64; ++t)
    enc_step<<<32 + nCvt, 512, 0, stream>>>(Gif, Gib, whFbf, whBbf, encf_bhh, encb_bhh,
                                            hbf, hf32, ebo, hcat, out_W, outWbf, nCvt, t);

  gemm_kernel<false, false, false><<<dim3(1, 4), 256, 0, stream>>>(
      hcat, 1024, fc_W, 1024, 0, fc_b, s0raw, 512, 1024, 32, 0);
  tanh_s0<<<32, 512, 0, stream>>>(s0raw, sf32, sbf);

  gemm_kernel<true, false, true><<<dim3(16, 4), 256, 0, stream>>>(
      ebo, 1024, attn_W, 1536, 512, nullptr, epf, 512, 1024, 2048, 0);
  gemm_kernel<true, false, true><<<dim3(16, 12), 256, 0, stream>>>(
      ebo, 1024, dec_Wih, 1536, 512, nullptr, EP2b, 1536, 1024, 2048, 0);

  for (int t = 0; t < 47; ++t) {
    dec_proj<<<32, 512, 0, stream>>>(Wcat, dec_bhh, sbf, gout, t);
    dec_attn<<<32, 512, 0, stream>>>(attn_v, epf, ebo, EP2b, Gie, gout,
                                     sbf, sf32, Zbf, t);
  }

  if (bigB) {
    hipFuncSetAttribute((const void*)gemm_big8,
                        hipFuncAttributeMaxDynamicSharedMemorySize, 131072);
    gemm_big8<<<750, 512, 131072, stream>>>(Zbf, outWbf, out_b, out);
  } else {
    gemm_kernel<true, false, false><<<dim3(12, 250), 256, 0, stream>>>(
        Zbf, 2048, out_W, 2048, 0, out_b, out, 32000, 2048, 1504, 32);
  }
}

// Round 10
// 1871.618 us; speedup vs baseline: 1.7612x; 1.0085x over previous
//
#include <hip/hip_runtime.h>
#include <stdint.h>
#include <stddef.h>

typedef __attribute__((ext_vector_type(8))) short short8;
typedef __attribute__((ext_vector_type(4))) float f32x4;
typedef unsigned int u32;

__device__ inline unsigned short f2bf(float f) {
  union { float f; uint32_t u; } v; v.f = f;
  uint32_t u = v.u;
  u += 0x7FFFu + ((u >> 16) & 1u);
  return (unsigned short)(u >> 16);
}
__device__ inline float bf2f(unsigned short h) {
  union { uint32_t u; float f; } v; v.u = ((uint32_t)h) << 16; return v.f;
}
__device__ inline short8 pack8(float4 a, float4 b) {
  short8 r;
  r[0] = (short)f2bf(a.x); r[1] = (short)f2bf(a.y);
  r[2] = (short)f2bf(a.z); r[3] = (short)f2bf(a.w);
  r[4] = (short)f2bf(b.x); r[5] = (short)f2bf(b.y);
  r[6] = (short)f2bf(b.z); r[7] = (short)f2bf(b.w);
  return r;
}
__device__ inline float tanh_fast(float x) {
  float xc = fminf(fmaxf(x, -9.f), 9.f);
  float e = __expf(2.f * xc);
  return (e - 1.f) * __builtin_amdgcn_rcpf(e + 1.f);
}
__device__ inline float sigm_fast(float x) {
  float xc = fminf(fmaxf(x, -30.f), 30.f);
  return __builtin_amdgcn_rcpf(1.f + __expf(-xc));
}
// async global->LDS, 16 bytes per lane (wave-uniform LDS base + lane*16)
__device__ inline void gl_lds16(const unsigned short* g, unsigned short* l) {
  __builtin_amdgcn_global_load_lds(
      (const __attribute__((address_space(1))) u32*)g,
      (__attribute__((address_space(3))) u32*)l, 16, 0, 0);
}

// Gather + bf16-convert embeddings.
__global__ __launch_bounds__(128) void prep_gather(
    const int* __restrict__ src, const int* __restrict__ trg,
    const float* __restrict__ emb,
    unsigned short* __restrict__ xbf, unsigned short* __restrict__ ebf,
    unsigned short* __restrict__ Zbf) {
  int r = blockIdx.x, tid = threadIdx.x;
  if (r < 2048) {
    int b = r & 31, s = r >> 5;
    int tok = src[b * 64 + s];
    const float* e = emb + (size_t)tok * 512;
    float4 v = *(const float4*)(e + tid * 4);
    unsigned short* dst = xbf + (size_t)r * 512 + tid * 4;
    dst[0] = f2bf(v.x); dst[1] = f2bf(v.y); dst[2] = f2bf(v.z); dst[3] = f2bf(v.w);
  } else {
    int rr = r - 2048;
    int t = rr >> 5, b = rr & 31;
    unsigned short* dst = ebf + (size_t)rr * 512 + tid * 4;
    if (t < 47) {
      int tok = trg[t * 32 + b];
      const float* e = emb + (size_t)tok * 512;
      float4 v = *(const float4*)(e + tid * 4);
      unsigned short q0 = f2bf(v.x), q1 = f2bf(v.y), q2 = f2bf(v.z), q3 = f2bf(v.w);
      dst[0] = q0; dst[1] = q1; dst[2] = q2; dst[3] = q3;
      unsigned short* zd = Zbf + (size_t)rr * 2048 + 1536 + tid * 4;
      zd[0] = q0; zd[1] = q1; zd[2] = q2; zd[3] = q3;
    } else {
      dst[0] = 0; dst[1] = 0; dst[2] = 0; dst[3] = 0;
    }
  }
}

// All recurrent-weight f32->bf16 conversions in one launch.
// Regions: [0,1536) encf_Whh; [1536,3072) encb_Whh; [3072,3584) attn_W cols 0..511
// (ld 1536); [3584,5120) dec_Whh -> Wcat rows 512..2047.
__global__ __launch_bounds__(64) void cvt_weights(
    const float* __restrict__ encfW, const float* __restrict__ encbW,
    const float* __restrict__ attnW, const float* __restrict__ decWhh,
    unsigned short* __restrict__ whFbf, unsigned short* __restrict__ whBbf,
    unsigned short* __restrict__ Wcat) {
  int r = blockIdx.x, c = threadIdx.x * 8;
  const float* s;
  unsigned short* d;
  if (r < 1536) { s = encfW + (size_t)r * 512 + c; d = whFbf + (size_t)r * 512 + c; }
  else if (r < 3072) { int q = r - 1536; s = encbW + (size_t)q * 512 + c; d = whBbf + (size_t)q * 512 + c; }
  else if (r < 3584) { int q = r - 3072; s = attnW + (size_t)q * 1536 + c; d = Wcat + (size_t)q * 512 + c; }
  else { int q = r - 3584; s = decWhh + (size_t)q * 512 + c; d = Wcat + (size_t)(q + 512) * 512 + c; }
  *(short8*)d = pack8(*(const float4*)s, *(const float4*)(s + 4));
}

// C[m,n] = sum_k A[m,k]*B[n,k] (+bias[n]). 128x128 tile, BK=32, 4 waves.
template <bool ABF, bool BBF, bool WBF>
__global__ __launch_bounds__(256) void gemm_kernel(
    const void* __restrict__ Av, int lda,
    const void* __restrict__ Bv, int ldb, int bco,
    const float* __restrict__ bias,
    void* __restrict__ Cv, int ldc,
    int K, int Mvalid, int row_off) {
  __shared__ __align__(16) unsigned short As[128 * 32];
  __shared__ __align__(16) unsigned short Bs[128 * 32];
  const int tid = threadIdx.x;
  const int m0 = blockIdx.x * 128, n0 = blockIdx.y * 128;
  const int w = tid >> 6, lane = tid & 63;
  const int wm = w >> 1, wn = w & 1;
  const int fr = lane & 15, fq = lane >> 4;
  f32x4 acc[4][4];
#pragma unroll
  for (int mi = 0; mi < 4; ++mi)
#pragma unroll
    for (int ni = 0; ni < 4; ++ni) acc[mi][ni] = (f32x4){0.f, 0.f, 0.f, 0.f};
  for (int k0 = 0; k0 < K; k0 += 32) {
#pragma unroll
    for (int p = 0; p < 2; ++p) {
      int idx = p * 256 + tid;
      int row = idx >> 2, seg = idx & 3;
      if (ABF) {
        const unsigned short* Ab = (const unsigned short*)Av;
        *(short8*)(As + row * 32 + seg * 8) =
            *(const short8*)(Ab + (size_t)(m0 + row) * lda + k0 + seg * 8);
      } else {
        const float* Af = (const float*)Av;
        const float* ap = Af + (size_t)(m0 + row) * lda + k0 + seg * 8;
        *(short8*)(As + row * 32 + seg * 8) = pack8(*(const float4*)ap, *(const float4*)(ap + 4));
      }
      if (BBF) {
        const unsigned short* Bb = (const unsigned short*)Bv;
        *(short8*)(Bs + row * 32 + seg * 8) =
            *(const short8*)(Bb + (size_t)(n0 + row) * ldb + bco + k0 + seg * 8);
      } else {
        const float* Bf = (const float*)Bv;
        const float* bp = Bf + (size_t)(n0 + row) * ldb + bco + k0 + seg * 8;
        *(short8*)(Bs + row * 32 + seg * 8) = pack8(*(const float4*)bp, *(const float4*)(bp + 4));
      }
    }
    __syncthreads();
    short8 af[4], bfr[4];
#pragma unroll
    for (int mi = 0; mi < 4; ++mi)
      af[mi] = *(const short8*)(As + (wm * 64 + mi * 16 + fr) * 32 + fq * 8);
#pragma unroll
    for (int ni = 0; ni < 4; ++ni)
      bfr[ni] = *(const short8*)(Bs + (wn * 64 + ni * 16 + fr) * 32 + fq * 8);
#pragma unroll
    for (int mi = 0; mi < 4; ++mi)
#pragma unroll
      for (int ni = 0; ni < 4; ++ni)
        acc[mi][ni] = __builtin_amdgcn_mfma_f32_16x16x32_bf16(af[mi], bfr[ni], acc[mi][ni], 0, 0, 0);
    __syncthreads();
  }
#pragma unroll
  for (int mi = 0; mi < 4; ++mi)
#pragma unroll
    for (int ni = 0; ni < 4; ++ni) {
      int col = n0 + wn * 64 + ni * 16 + fr;
      float bv = bias ? bias[col] : 0.f;
#pragma unroll
      for (int j = 0; j < 4; ++j) {
        int rowm = m0 + wm * 64 + mi * 16 + fq * 4 + j;
        if (rowm < Mvalid) {
          float val = acc[mi][ni][j] + bv;
          if (WBF)
            ((unsigned short*)Cv)[(size_t)(rowm + row_off) * ldc + col] = f2bf(val);
          else
            ((float*)Cv)[(size_t)(rowm + row_off) * ldc + col] = val;
        }
      }
    }
}

// Output projection, 8-phase 256x256 schedule. Swizzle (G4): within each
// half-tile, byte ^= ((row&7)<<4) — spreads 8 consecutive 128B rows across
// 8 distinct 16B bank slots. Applied as inverse-permuted global source
// (gl_lds writes linearly) + same XOR on ds_read addresses.
__global__ __launch_bounds__(512, 1) void gemm_big8(
    const unsigned short* __restrict__ A,
    const unsigned short* __restrict__ B,
    const float* __restrict__ bias,
    float* __restrict__ C) {
  extern __shared__ char lds[];
  char* LA = lds;
  char* LB = lds + 65536;
  const int tid = threadIdx.x;
  const int w = tid >> 6, lane = tid & 63;
  // bijective XCD swizzle: 750 wgs = 8 XCDs, q=93, r=6
  int wg = blockIdx.x;
  {
    int x = wg & 7, i = wg >> 3;
    wg = (x < 6 ? x * 94 : 564 + (x - 6) * 93) + i;
  }
  const int m0 = (wg % 6) * 256, n0 = (wg / 6) * 256;
  const int wm = w >> 2, wn = w & 3;
  const int fr = lane & 15, fq = lane >> 4;

  // stage one half-tile (128 rows x 64 cols bf16 = 16KB) of tile kt into buf c
  auto stage = [&](const unsigned short* G, char* L, int rowbase, int kt, int h, int c) {
#pragma unroll
    for (int j = 0; j < 2; ++j) {
      int pbh = j * 8192 + w * 1024;           // wave-uniform LDS offset
      int pl = pbh + lane * 16;                // this lane's physical byte
      int lb = pl ^ (((pl >> 7) & 7) << 4);    // logical byte (involution)
      int rl = lb >> 7, ch = (lb >> 4) & 7;
      gl_lds16(G + (size_t)(rowbase + h * 128 + rl) * 2048 + kt * 64 + ch * 8,
               (unsigned short*)(L + c * 32768 + h * 16384 + pbh));
    }
  };

  f32x4 acc[8][4];
#pragma unroll
  for (int mi = 0; mi < 8; ++mi)
#pragma unroll
    for (int ni = 0; ni < 4; ++ni) acc[mi][ni] = (f32x4){0.f, 0.f, 0.f, 0.f};

  // prologue: tile 0 into buf 0
  stage(A, LA, m0, 0, 0, 0); stage(B, LB, n0, 0, 0, 0);
  stage(A, LA, m0, 0, 1, 0); stage(B, LB, n0, 0, 1, 0);
  asm volatile("s_waitcnt vmcnt(0)" ::: "memory");
  __builtin_amdgcn_s_barrier();

  short8 bfrag[8];
  for (int kt = 0; kt < 32; ++kt) {
    const int c = kt & 1;
    char* Abuf = LA + c * 32768;
    char* Bbuf = LB + c * 32768;
#pragma unroll
    for (int p = 0; p < 4; ++p) {
      if (kt < 31) {
        if (p == 0) {
          stage(A, LA, m0, kt + 1, 0, c ^ 1);
          stage(B, LB, n0, kt + 1, 0, c ^ 1);
        } else if (p == 1) {
          stage(A, LA, m0, kt + 1, 1, c ^ 1);
          stage(B, LB, n0, kt + 1, 1, c ^ 1);
        }
      }
      if (p == 0) {
#pragma unroll
        for (int ni = 0; ni < 4; ++ni)
#pragma unroll
          for (int ks = 0; ks < 2; ++ks) {
            int n = wn * 64 + ni * 16 + fr;
            int h = n >> 7, nl = n & 127;
            int lb = nl * 128 + ks * 64 + fq * 16;
            int pb = lb ^ (((lb >> 7) & 7) << 4);
            bfrag[ni * 2 + ks] = *(const short8*)(Bbuf + h * 16384 + pb);
          }
      }
      short8 afrag[4];
#pragma unroll
      for (int q = 0; q < 2; ++q)
#pragma unroll
        for (int ks = 0; ks < 2; ++ks) {
          int r = wm * 128 + (2 * p + q) * 16 + fr;
          int h = r >> 7, rl = r & 127;
          int lb = rl * 128 + ks * 64 + fq * 16;
          int pb = lb ^ (((lb >> 7) & 7) << 4);
          afrag[q * 2 + ks] = *(const short8*)(Abuf + h * 16384 + pb);
        }
      __builtin_amdgcn_s_setprio(1);
#pragma unroll
      for (int q = 0; q < 2; ++q)
#pragma unroll
        for (int ni = 0; ni < 4; ++ni)
#pragma unroll
          for (int ks = 0; ks < 2; ++ks)
            acc[2 * p + q][ni] = __builtin_amdgcn_mfma_f32_16x16x32_bf16(
                afrag[q * 2 + ks], bfrag[ni * 2 + ks], acc[2 * p + q][ni], 0, 0, 0);
      __builtin_amdgcn_s_setprio(0);
      if (p == 3) asm volatile("s_waitcnt vmcnt(0)" ::: "memory");
      __builtin_amdgcn_s_barrier();
    }
  }
#pragma unroll
  for (int mi = 0; mi < 8; ++mi)
#pragma unroll
    for (int ni = 0; ni < 4; ++ni) {
      int col = n0 + wn * 64 + ni * 16 + fr;
      float bv = bias[col];
#pragma unroll
      for (int j = 0; j < 4; ++j) {
        int row = m0 + wm * 128 + mi * 16 + fq * 4 + j;
        if (row < 1504) C[(size_t)(row + 32) * 32000 + col] = acc[mi][ni][j] + bv;
      }
    }
}

// One encoder GRU step, both directions. Blocks 0..31: dir=blk>>4, 32-d slice.
// Blocks 32..231: piggyback out_W f32->bf16 conversion (idle-CU work).
__global__ __launch_bounds__(512) void enc_step(
    const float* __restrict__ Gif, const float* __restrict__ Gib,
    const unsigned short* __restrict__ whFbf, const unsigned short* __restrict__ whBbf,
    const float* __restrict__ bhhF, const float* __restrict__ bhhB,
    unsigned short* __restrict__ hbf,   // [dir][2][32][512] bf16
    float* __restrict__ hf32,           // [dir][2][32][512] f32
    unsigned short* __restrict__ ebo,   // [b][s][1024] bf16
    float* __restrict__ hcat,           // [b][1024] f32
    const float* __restrict__ outW, unsigned short* __restrict__ outWbf, int nCvt,
    int t) {
  const int blk = blockIdx.x, tid = threadIdx.x;
  if (blk >= 32) {
    if (blk - 32 < nCvt) {
      size_t base4 = ((size_t)t * nCvt + (blk - 32)) * 1280;
      for (int i = tid; i < 1280; i += 512) {
        float4 v = ((const float4*)outW)[base4 + i];
        unsigned short* d = outWbf + (base4 + i) * 4;
        d[0] = f2bf(v.x); d[1] = f2bf(v.y); d[2] = f2bf(v.z); d[3] = f2bf(v.w);
      }
    }
    return;
  }
  const int dir = blk >> 4, slice = blk & 15, D0 = slice * 32;
  const unsigned short* Wbf = dir ? whBbf : whFbf;
  const float* Gi = dir ? Gib : Gif;
  const float* bhh = dir ? bhhB : bhhF;
  __shared__ __align__(16) unsigned short hlds[32 * 520];
  __shared__ __align__(16) float gl[96 * 33];
  const unsigned short* hb = hbf + dir * 32768 + (t & 1) * 16384;
  for (int c = tid; c < 32 * 64; c += 512) {
    int r = c >> 6, seg = c & 63;
    *(short8*)(hlds + r * 520 + seg * 8) = *(const short8*)(hb + r * 512 + seg * 8);
  }
  __syncthreads();
  const int w = tid >> 6, lane = tid & 63, fr = lane & 15, fq = lane >> 4;
  if (w < 6) {
    int row = w * 16 + fr;
    int gr = (row >> 5) * 512 + D0 + (row & 31);
    const unsigned short* wrow = Wbf + (size_t)gr * 512;
    f32x4 acc0 = {0.f, 0.f, 0.f, 0.f}, acc1 = {0.f, 0.f, 0.f, 0.f};
#pragma unroll
    for (int k0 = 0; k0 < 512; k0 += 32) {
      short8 bq = *(const short8*)(wrow + k0 + fq * 8);
      short8 a0 = *(const short8*)(hlds + fr * 520 + k0 + fq * 8);
      short8 a1 = *(const short8*)(hlds + (16 + fr) * 520 + k0 + fq * 8);
      acc0 = __builtin_amdgcn_mfma_f32_16x16x32_bf16(a0, bq, acc0, 0, 0, 0);
      acc1 = __builtin_amdgcn_mfma_f32_16x16x32_bf16(a1, bq, acc1, 0, 0, 0);
    }
#pragma unroll
    for (int j = 0; j < 4; ++j) {
      gl[row * 33 + fq * 4 + j] = acc0[j];
      gl[row * 33 + 16 + fq * 4 + j] = acc1[j];
    }
  }
  __syncthreads();
  const int srow = dir ? 63 - t : t;
  unsigned short* hnb = hbf + dir * 32768 + ((t + 1) & 1) * 16384;
  const float* hcur = hf32 + dir * 32768 + (t & 1) * 16384;
  float* hnf = hf32 + dir * 32768 + ((t + 1) & 1) * 16384;
#pragma unroll
  for (int rep = 0; rep < 2; ++rep) {
    int idx = rep * 512 + tid, b = idx >> 5, dl = idx & 31, d = D0 + dl;
    float ar = gl[dl * 33 + b] + bhh[d];
    float az = gl[(32 + dl) * 33 + b] + bhh[512 + d];
    float an = gl[(64 + dl) * 33 + b] + bhh[1024 + d];
    const float* gi = Gi + ((size_t)srow * 32 + b) * 1536;
    float r = sigm_fast(gi[d] + ar);
    float z = sigm_fast(gi[512 + d] + az);
    float n = tanh_fast(gi[1024 + d] + r * an);
    float h2 = (1.f - z) * n + z * hcur[b * 512 + d];
    hnb[b * 512 + d] = f2bf(h2);
    hnf[b * 512 + d] = h2;
    ebo[((size_t)b * 64 + srow) * 1024 + (size_t)dir * 512 + d] = f2bf(h2);
    if (t == 63) hcat[(size_t)b * 1024 + (size_t)dir * 512 + d] = h2;
  }
}

__global__ __launch_bounds__(512) void tanh_s0(const float* __restrict__ s0raw,
                                               float* __restrict__ sf32,
                                               unsigned short* __restrict__ sbf) {
  int idx = blockIdx.x * 512 + threadIdx.x;
  float v = tanhf(s0raw[idx]);
  sf32[idx] = v;
  sbf[idx] = f2bf(v);
}

// Decoder step part 1: gout[b][n] = s_t[b] . Wcat[n] (+decBhh for n>=512).
__global__ __launch_bounds__(512) void dec_proj(
    const unsigned short* __restrict__ Wcat, const float* __restrict__ decBhh,
    const unsigned short* __restrict__ sbf, float* __restrict__ gout, int t) {
  const int g = blockIdx.x, tid = threadIdx.x;
  __shared__ __align__(16) unsigned short slds[32 * 520];
  const unsigned short* sb = sbf + (t & 1) * 16384;
  for (int c = tid; c < 32 * 64; c += 512) {
    int r = c >> 6, seg = c & 63;
    *(short8*)(slds + r * 520 + seg * 8) = *(const short8*)(sb + r * 512 + seg * 8);
  }
  __syncthreads();
  const int w = tid >> 6, lane = tid & 63, fr = lane & 15, fq = lane >> 4;
  const int mt = w >> 2, nt = w & 3;
  int rc = g * 64 + nt * 16 + fr;
  const unsigned short* wrow = Wcat + (size_t)rc * 512;
  f32x4 acc = {0.f, 0.f, 0.f, 0.f};
#pragma unroll
  for (int k0 = 0; k0 < 512; k0 += 32) {
    short8 a = *(const short8*)(slds + (mt * 16 + fr) * 520 + k0 + fq * 8);
    short8 bq = *(const short8*)(wrow + k0 + fq * 8);
    acc = __builtin_amdgcn_mfma_f32_16x16x32_bf16(a, bq, acc, 0, 0, 0);
  }
  float bv = rc < 512 ? 0.f : decBhh[rc - 512];
#pragma unroll
  for (int j = 0; j < 4; ++j)
    gout[(size_t)(mt * 16 + fq * 4 + j) * 2048 + rc] = acc[j] + bv;
}

// Decoder step part 2: scores, softmax, context, gic, gates. One block per batch.
__global__ __launch_bounds__(512) void dec_attn(
    const float* __restrict__ attnV,
    const unsigned short* __restrict__ epf, const unsigned short* __restrict__ ebo,
    const unsigned short* __restrict__ EP2b, const float* __restrict__ Gie,
    const float* __restrict__ gout,
    unsigned short* __restrict__ sbf, float* __restrict__ sf32,
    unsigned short* __restrict__ Zbf, int t) {
  const int b = blockIdx.x, tid = threadIdx.x;
  __shared__ __align__(16) float gout_f[2048];
  __shared__ float raw[64], aaw[64];
  __shared__ float vlds[512];
  vlds[tid] = attnV[tid];
  *(float4*)(gout_f + tid * 4) = *(const float4*)(gout + (size_t)b * 2048 + tid * 4);
  __syncthreads();
  const int s_i = tid >> 3, l8 = tid & 7;
  {
    float part = 0.f;
    const float* gp = gout_f + l8 * 64;
    const unsigned short* ep = epf + ((size_t)b * 64 + s_i) * 512 + l8 * 64;
    const float* vv = vlds + l8 * 64;
#pragma unroll
    for (int jc = 0; jc < 8; ++jc) {
      short8 e8 = *(const short8*)(ep + jc * 8);
      float4 g0 = *(const float4*)(gp + jc * 8);
      float4 g1 = *(const float4*)(gp + jc * 8 + 4);
      float4 v0 = *(const float4*)(vv + jc * 8);
      float4 v1 = *(const float4*)(vv + jc * 8 + 4);
      part += tanh_fast(g0.x + bf2f((unsigned short)e8[0])) * v0.x;
      part += tanh_fast(g0.y + bf2f((unsigned short)e8[1])) * v0.y;
      part += tanh_fast(g0.z + bf2f((unsigned short)e8[2])) * v0.z;
      part += tanh_fast(g0.w + bf2f((unsigned short)e8[3])) * v0.w;
      part += tanh_fast(g1.x + bf2f((unsigned short)e8[4])) * v1.x;
      part += tanh_fast(g1.y + bf2f((unsigned short)e8[5])) * v1.y;
      part += tanh_fast(g1.z + bf2f((unsigned short)e8[6])) * v1.z;
      part += tanh_fast(g1.w + bf2f((unsigned short)e8[7])) * v1.w;
    }
    part += __shfl_xor(part, 1);
    part += __shfl_xor(part, 2);
    part += __shfl_xor(part, 4);
    if (l8 == 0) raw[s_i] = part;
  }
  __syncthreads();
  if (tid < 64) {
    float x = raw[tid];
    float m = x;
#pragma unroll
    for (int k = 1; k < 64; k <<= 1) m = fmaxf(m, __shfl_xor(m, k));
    float e = __expf(x - m);
    float s = e;
#pragma unroll
    for (int k = 1; k < 64; k <<= 1) s += __shfl_xor(s, k);
    aaw[tid] = e * __builtin_amdgcn_rcpf(s);
  }
  __syncthreads();
  float c0 = 0.f, c1 = 0.f, g0a = 0.f, g1a = 0.f, g2a = 0.f;
  {
    const unsigned short* eb = ebo + (size_t)b * 64 * 1024 + tid;
    const unsigned short* e2 = EP2b + (size_t)b * 64 * 1536 + tid;
#pragma unroll 8
    for (int s2 = 0; s2 < 64; ++s2) {
      float a = aaw[s2];
      c0 += a * bf2f(eb[(size_t)s2 * 1024]);
      c1 += a * bf2f(eb[(size_t)s2 * 1024 + 512]);
      g0a += a * bf2f(e2[(size_t)s2 * 1536]);
      g1a += a * bf2f(e2[(size_t)s2 * 1536 + 512]);
      g2a += a * bf2f(e2[(size_t)s2 * 1536 + 1024]);
    }
  }
  const float* gie = Gie + ((size_t)t * 32 + b) * 1536;
  float sprev = sf32[(t & 1) * 16384 + b * 512 + tid];
  float rr = sigm_fast(gie[tid] + g0a + gout_f[512 + tid]);
  float zz = sigm_fast(gie[512 + tid] + g1a + gout_f[1024 + tid]);
  float nn = tanh_fast(gie[1024 + tid] + g2a + rr * gout_f[1536 + tid]);
  float s2v = (1.f - zz) * nn + zz * sprev;
  sbf[((t + 1) & 1) * 16384 + b * 512 + tid] = f2bf(s2v);
  sf32[((t + 1) & 1) * 16384 + b * 512 + tid] = s2v;
  size_t zrow = ((size_t)t * 32 + b) * 2048;
  Zbf[zrow + tid] = f2bf(s2v);
  Zbf[zrow + 512 + tid] = f2bf(c0);
  Zbf[zrow + 1024 + tid] = f2bf(c1);
}

extern "C" void kernel_launch(void* const* d_in, const int* in_sizes, int n_in,
                              void* d_out, int out_size, void* d_ws, size_t ws_size,
                              hipStream_t stream) {
  (void)in_sizes; (void)n_in; (void)out_size;
  const int* src = (const int*)d_in[0];
  const int* trg = (const int*)d_in[1];
  const float* emb = (const float*)d_in[2];
  const float* encf_Wih = (const float*)d_in[3];
  const float* encf_Whh = (const float*)d_in[4];
  const float* encf_bih = (const float*)d_in[5];
  const float* encf_bhh = (const float*)d_in[6];
  const float* encb_Wih = (const float*)d_in[7];
  const float* encb_Whh = (const float*)d_in[8];
  const float* encb_bih = (const float*)d_in[9];
  const float* encb_bhh = (const float*)d_in[10];
  const float* fc_W = (const float*)d_in[11];
  const float* fc_b = (const float*)d_in[12];
  const float* attn_W = (const float*)d_in[13];
  const float* attn_v = (const float*)d_in[14];
  const float* dec_Wih = (const float*)d_in[15];
  const float* dec_Whh = (const float*)d_in[16];
  const float* dec_bih = (const float*)d_in[17];
  const float* dec_bhh = (const float*)d_in[18];
  const float* out_W = (const float*)d_in[19];
  const float* out_b = (const float*)d_in[20];
  float* out = (float*)d_out;

  char* p = (char*)d_ws;
  size_t off = 0;
  auto alloc = [&](size_t bytes) {
    void* r = p + off;
    off = (off + bytes + 255) & ~(size_t)255;
    return r;
  };
  unsigned short* xbf = (unsigned short*)alloc((size_t)2048 * 512 * 2);
  unsigned short* ebf = (unsigned short*)alloc((size_t)1536 * 512 * 2);
  unsigned short* Zbf = (unsigned short*)alloc((size_t)1536 * 2048 * 2);
  float* Gif = (float*)alloc((size_t)2048 * 1536 * 4);
  float* Gib = (float*)alloc((size_t)2048 * 1536 * 4);
  float* Gie = (float*)alloc((size_t)1536 * 1536 * 4);
  unsigned short* ebo = (unsigned short*)alloc((size_t)2048 * 1024 * 2);
  unsigned short* epf = (unsigned short*)alloc((size_t)2048 * 512 * 2);
  unsigned short* EP2b = (unsigned short*)alloc((size_t)2048 * 1536 * 2);
  unsigned short* whFbf = (unsigned short*)alloc((size_t)1536 * 512 * 2);
  unsigned short* whBbf = (unsigned short*)alloc((size_t)1536 * 512 * 2);
  unsigned short* Wcat = (unsigned short*)alloc((size_t)2048 * 512 * 2);
  unsigned short* hbf = (unsigned short*)alloc((size_t)2 * 2 * 32 * 512 * 2);
  float* hf32 = (float*)alloc((size_t)2 * 2 * 32 * 512 * 4);
  float* hcat = (float*)alloc((size_t)32 * 1024 * 4);
  float* s0raw = (float*)alloc((size_t)32 * 512 * 4);
  unsigned short* sbf = (unsigned short*)alloc((size_t)2 * 32 * 512 * 2);
  float* sf32 = (float*)alloc((size_t)2 * 32 * 512 * 4);
  float* gout = (float*)alloc((size_t)32 * 2048 * 4);
  unsigned short* outWbf = (unsigned short*)alloc((size_t)32000 * 2048 * 2);
  const bool bigB = (off <= ws_size);

  hipMemsetAsync(hbf, 0, (size_t)2 * 2 * 32 * 512 * 2, stream);
  hipMemsetAsync(hf32, 0, (size_t)2 * 2 * 32 * 512 * 4, stream);
  hipMemsetAsync(d_out, 0, (size_t)32 * 32000 * 4, stream);

  prep_gather<<<3584, 128, 0, stream>>>(src, trg, emb, xbf, ebf, Zbf);
  cvt_weights<<<5120, 64, 0, stream>>>(encf_Whh, encb_Whh, attn_W, dec_Whh,
                                       whFbf, whBbf, Wcat);

  gemm_kernel<true, false, false><<<dim3(16, 12), 256, 0, stream>>>(
      xbf, 512, encf_Wih, 512, 0, encf_bih, Gif, 1536, 512, 2048, 0);
  gemm_kernel<true, false, false><<<dim3(16, 12), 256, 0, stream>>>(
      xbf, 512, encb_Wih, 512, 0, encb_bih, Gib, 1536, 512, 2048, 0);
  gemm_kernel<true, false, false><<<dim3(12, 12), 256, 0, stream>>>(
      ebf, 512, dec_Wih, 1536, 0, dec_bih, Gie, 1536, 512, 1536, 0);

  // encoder steps; piggyback out_W bf16 conversion on idle CUs (200 blocks/step)
  const int nCvt = bigB ? 200 : 0;
  for (int t = 0; t < 64; ++t)
    enc_step<<<32 + nCvt, 512, 0, stream>>>(Gif, Gib, whFbf, whBbf, encf_bhh, encb_bhh,
                                            hbf, hf32, ebo, hcat, out_W, outWbf, nCvt, t);

  gemm_kernel<false, false, false><<<dim3(1, 4), 256, 0, stream>>>(
      hcat, 1024, fc_W, 1024, 0, fc_b, s0raw, 512, 1024, 32, 0);
  tanh_s0<<<32, 512, 0, stream>>>(s0raw, sf32, sbf);

  gemm_kernel<true, false, true><<<dim3(16, 4), 256, 0, stream>>>(
      ebo, 1024, attn_W, 1536, 512, nullptr, epf, 512, 1024, 2048, 0);
  gemm_kernel<true, false, true><<<dim3(16, 12), 256, 0, stream>>>(
      ebo, 1024, dec_Wih, 1536, 512, nullptr, EP2b, 1536, 1024, 2048, 0);

  for (int t = 0; t < 47; ++t) {
    dec_proj<<<32, 512, 0, stream>>>(Wcat, dec_bhh, sbf, gout, t);
    dec_attn<<<32, 512, 0, stream>>>(attn_v, epf, ebo, EP2b, Gie, gout,
                                     sbf, sf32, Zbf, t);
  }

  if (bigB) {
    hipFuncSetAttribute((const void*)gemm_big8,
                        hipFuncAttributeMaxDynamicSharedMemorySize, 131072);
    gemm_big8<<<750, 512, 131072, stream>>>(Zbf, outWbf, out_b, out);
  } else {
    gemm_kernel<true, false, false><<<dim3(12, 250), 256, 0, stream>>>(
        Zbf, 2048, out_W, 2048, 0, out_b, out, 32000, 2048, 1504, 32);
  }
}